// Round 1
// baseline (594.226 us; speedup 1.0000x reference)
//
#include <hip/hip_runtime.h>
#include <cmath>

#define DPROJ 1552

// Workspace layout (float offsets)
constexpr size_t OFF_M   = 0;                      // 3*1552 fused weight
constexpr size_t OFF_C   = 4656;                   // 1552 fused bias
constexpr size_t OFF_XBC = 6400;                   // 16384*1024 pre-conv xBC; later aliased as y (16384*512)
constexpr size_t OFF_DT  = OFF_XBC + 16777216;     // 16384*16 softplus(dt)
constexpr size_t OFF_XS  = OFF_DT + 262144;        // 16384*512 x heads (B,L,16,32)
constexpr size_t OFF_BC  = OFF_XS + 8388608;       // 16384*512: per row [B(256) | C(256)]
constexpr size_t OFF_CUM = OFF_BC + 8388608;       // (b,c,h)*128 cumsum(dt*A)
constexpr size_t OFF_CDC = OFF_CUM + 262144;       // (b,c,h) chunk decay
constexpr size_t OFF_CB  = OFF_CDC + 2048;         // (b,c)*128*128  C·B^T
constexpr size_t OFF_ST  = OFF_CB + 2097152;       // (b,c,h)*32*256 states -> prev (in-place)
// total = 52,961,536 floats = ~212 MB

__device__ __forceinline__ float sigm(float x){ return 1.0f/(1.0f + __expf(-x)); }

// ---------------- K0: fuse fc0 into in_proj: M = fc0_w@W (3x1552), c = fc0_b@W ----
__global__ __launch_bounds__(256) void k0_prep(const float* __restrict__ fc0_w,
                                               const float* __restrict__ fc0_b,
                                               const float* __restrict__ W,
                                               float* __restrict__ ws){
  int j = blockIdx.x*256 + threadIdx.x;
  if (j >= DPROJ) return;
  float m0=0.f,m1=0.f,m2=0.f,cc=0.f;
  for (int d=0; d<128; ++d){
    float w = W[(size_t)d*DPROJ + j];
    m0 = fmaf(fc0_w[d],       w, m0);
    m1 = fmaf(fc0_w[128+d],   w, m1);
    m2 = fmaf(fc0_w[256+d],   w, m2);
    cc = fmaf(fc0_b[d],       w, cc);
  }
  ws[OFF_M + j] = m0; ws[OFF_M + DPROJ + j] = m1; ws[OFF_M + 2*DPROJ + j] = m2;
  ws[OFF_C + j] = cc;
}

// ---------------- K1: gather pixel, project to xBC (1024) + dt (16) --------------
__global__ __launch_bounds__(256) void k1_proj(const float* __restrict__ x,
                                               const float* __restrict__ dt_bias,
                                               float* __restrict__ ws){
  int r = blockIdx.x; int b = r>>13; int l = r & 8191;
  int h, w;
  if (l < 4096){ h = l>>6; w = l&63; }
  else { int l2 = l-4096; h = 63-(l2>>6); w = 63-(l2&63); }
  const float* xb = x + (size_t)b*3*4096;
  float x0 = xb[h*64+w], x1 = xb[4096 + h*64+w], x2 = xb[8192 + h*64+w];
  const float* M = ws + OFF_M; const float* Cc = ws + OFF_C;
  float* xbc = ws + OFF_XBC + (size_t)r*1024;
  float* dtp = ws + OFF_DT  + (size_t)r*16;
  for (int j = 512 + threadIdx.x; j < DPROJ; j += 256){
    float v = Cc[j];
    v = fmaf(x0, M[j], v);
    v = fmaf(x1, M[DPROJ+j], v);
    v = fmaf(x2, M[2*DPROJ+j], v);
    if (j < 1536) xbc[j-512] = v;
    else {
      int hh = j - 1536;
      float t = v + dt_bias[hh];
      dtp[hh] = (t > 20.f) ? t : log1pf(__expf(t));   // softplus
    }
  }
}

// ---------------- K2: depthwise causal conv(4) + silu, split xs / BC ------------
__global__ __launch_bounds__(256) void k2_conv(const float* __restrict__ conv_w,
                                               const float* __restrict__ conv_b,
                                               float* __restrict__ ws){
  int r = blockIdx.x; int b = r>>13; int l = r & 8191;
  const float* xbc = ws + OFF_XBC;
  float* xs = ws + OFF_XS; float* bc = ws + OFF_BC;
  size_t rowb = (size_t)b*8192;
  for (int ch = threadIdx.x; ch < 1024; ch += 256){
    float acc = conv_b[ch];
    #pragma unroll
    for (int k=0;k<4;++k){
      int li = l-3+k;
      if (li >= 0) acc = fmaf(xbc[(rowb+li)*1024 + ch], conv_w[ch*4+k], acc);
    }
    float v = acc * sigm(acc);
    if (ch < 512) xs[(size_t)r*512 + ch] = v;
    else          bc[(size_t)r*512 + (ch-512)] = v;
  }
}

// ---------------- K3: per (b,c,h) inclusive cumsum of dt*A ----------------------
__global__ __launch_bounds__(128) void k3_cum(const float* __restrict__ A_log,
                                              float* __restrict__ ws){
  int bi = blockIdx.x;                    // (b*64+c)*16 + h
  int h = bi & 15;
  int t = threadIdx.x;
  __shared__ float s[128];
  float A = -__expf(A_log[h]);
  size_t row = (size_t)(bi>>4)*128 + t;   // b*8192 + c*128 + t
  float a = ws[OFF_DT + row*16 + h] * A;
  s[t] = a; __syncthreads();
  for (int off=1; off<128; off<<=1){
    float v = (t>=off) ? s[t-off] : 0.f;
    __syncthreads();
    s[t] += v;
    __syncthreads();
  }
  ws[OFF_CUM + (size_t)bi*128 + t] = s[t];
  if (t==127) ws[OFF_CDC + bi] = __expf(s[127]);
}

// ---------------- K4a: CB[t,s] = sum_n C[t,n]*B[s,n]  (shared across heads) -----
__global__ __launch_bounds__(256) void k4a_cb(float* __restrict__ ws){
  int bi = blockIdx.x;                    // (b*64+c)*2 + thalf
  int th = bi & 1; int bc_i = bi >> 1;
  __shared__ float sCt[32*65];            // [n][t_local 0..63] pad 65
  __shared__ float sBt[32*132];           // [n][s 0..127] pad 132 (16B-aligned rows)
  const float* bcp = ws + OFF_BC;
  float* cb = ws + OFF_CB + (size_t)bc_i*16384;
  size_t rb = (size_t)bc_i*128;           // row base
  int tq = threadIdx.x >> 2;              // 0..63
  int sq = threadIdx.x & 3;               // s quarter
  float acc[32];
  #pragma unroll
  for (int j=0;j<32;++j) acc[j]=0.f;
  for (int nt=0; nt<8; ++nt){
    int n0 = nt*32;
    for (int idx = threadIdx.x; idx < 2048; idx += 256){
      int tl = idx >> 5, nl = idx & 31;
      sCt[nl*65 + tl] = bcp[(rb + th*64 + tl)*512 + 256 + n0 + nl];
    }
    for (int idx = threadIdx.x; idx < 4096; idx += 256){
      int sl = idx >> 5, nl = idx & 31;
      sBt[nl*132 + sl] = bcp[(rb + sl)*512 + n0 + nl];
    }
    __syncthreads();
    #pragma unroll 4
    for (int nl=0; nl<32; ++nl){
      float cv = sCt[nl*65 + tq];
      const float4* bb = (const float4*)&sBt[nl*132 + sq*32];
      #pragma unroll
      for (int j4=0;j4<8;++j4){
        float4 b4 = bb[j4];
        acc[j4*4+0] = fmaf(cv, b4.x, acc[j4*4+0]);
        acc[j4*4+1] = fmaf(cv, b4.y, acc[j4*4+1]);
        acc[j4*4+2] = fmaf(cv, b4.z, acc[j4*4+2]);
        acc[j4*4+3] = fmaf(cv, b4.w, acc[j4*4+3]);
      }
    }
    __syncthreads();
  }
  int t = th*64 + tq;
  float4* outp = (float4*)&cb[t*128 + sq*32];
  #pragma unroll
  for (int j4=0;j4<8;++j4)
    outp[j4] = make_float4(acc[j4*4],acc[j4*4+1],acc[j4*4+2],acc[j4*4+3]);
}

// ------- K4b: per (b,c,h): y_intra = (CB*decay*dt)@x ; states = (w*x)^T B -------
__global__ __launch_bounds__(256) void k4b_intra_states(float* __restrict__ ws){
  int bi = blockIdx.x;                    // (b*64+c)*16 + h
  int h = bi & 15; int bc_i = bi >> 4;
  __shared__ float sX[128*32];            // x chunk [s][p]
  __shared__ float sU[8192];              // union: attn tile [128][64] OR B tile [32][256]
  __shared__ float sCum[128], sDt[128], sW[128];
  size_t rb = (size_t)bc_i*128;
  const float* xs   = ws + OFF_XS;
  const float* bcp  = ws + OFF_BC;
  const float* cumb = ws + OFF_CUM + (size_t)bi*128;
  const float* cbp  = ws + OFF_CB + (size_t)bc_i*16384;
  for (int idx = threadIdx.x; idx < 4096; idx += 256){
    int s = idx>>5, p = idx&31;
    sX[idx] = xs[(rb+s)*512 + h*32 + p];
  }
  if (threadIdx.x < 128){
    int t = threadIdx.x;
    sCum[t] = cumb[t];
    sDt[t]  = ws[OFF_DT + (rb+t)*16 + h];
  }
  __syncthreads();
  if (threadIdx.x < 128){
    int t = threadIdx.x;
    sW[t] = __expf(sCum[127] - sCum[t]) * sDt[t];
  }
  int p = threadIdx.x & 31, tg = threadIdx.x >> 5;
  float acc[16];
  #pragma unroll
  for (int i=0;i<16;++i) acc[i]=0.f;
  // ---- phase A: y_intra, s-tiles of 64 ----
  for (int s0=0; s0<128; s0+=64){
    __syncthreads();
    for (int idx = threadIdx.x; idx < 8192; idx += 256){
      int t = idx>>6, sl = idx&63; int s = s0+sl;
      float v = 0.f;
      if (t >= s) v = cbp[t*128+s] * __expf(sCum[t]-sCum[s]) * sDt[s];
      sU[t*64+sl] = v;
    }
    __syncthreads();
    #pragma unroll 4
    for (int sl=0; sl<64; ++sl){
      float xv = sX[(s0+sl)*32 + p];
      #pragma unroll
      for (int ti=0; ti<16; ++ti)
        acc[ti] = fmaf(sU[(tg*16+ti)*64 + sl], xv, acc[ti]);
    }
  }
  float* y = ws + OFF_XBC;                // alias (xbc dead)
  #pragma unroll
  for (int ti=0; ti<16; ++ti){
    int t = tg*16+ti;
    y[(rb+t)*512 + h*32 + p] = acc[ti];
  }
  // ---- phase B: states[p][n] = sum_s w[s]*x[s][p]*B[s][n] ----
  float acc2[32];
  #pragma unroll
  for (int i=0;i<32;++i) acc2[i]=0.f;
  int ng = tg;                            // n group: n0 = ng*32
  for (int s0=0; s0<128; s0+=32){
    __syncthreads();
    for (int idx = threadIdx.x; idx < 8192; idx += 256){
      int sl = idx>>8, n = idx&255;
      sU[idx] = bcp[(rb+s0+sl)*512 + n];  // B part
    }
    __syncthreads();
    #pragma unroll 4
    for (int sl=0; sl<32; ++sl){
      int s = s0+sl;
      float xw = sX[s*32 + p] * sW[s];
      const float4* bb = (const float4*)&sU[sl*256 + ng*32];
      #pragma unroll
      for (int j4=0;j4<8;++j4){
        float4 b4 = bb[j4];
        acc2[j4*4+0] = fmaf(xw, b4.x, acc2[j4*4+0]);
        acc2[j4*4+1] = fmaf(xw, b4.y, acc2[j4*4+1]);
        acc2[j4*4+2] = fmaf(xw, b4.z, acc2[j4*4+2]);
        acc2[j4*4+3] = fmaf(xw, b4.w, acc2[j4*4+3]);
      }
    }
  }
  float* st = ws + OFF_ST + (size_t)bi*8192;
  float4* stp = (float4*)&st[p*256 + ng*32];
  #pragma unroll
  for (int j4=0;j4<8;++j4)
    stp[j4] = make_float4(acc2[j4*4],acc2[j4*4+1],acc2[j4*4+2],acc2[j4*4+3]);
}

// ---------------- K5: sequential chunk scan, states -> prev (in place) ----------
__global__ __launch_bounds__(256) void k5_scan(float* __restrict__ ws){
  int g = blockIdx.x*256 + threadIdx.x;   // 262144 threads
  int n = g & 255; int p = (g>>8)&31; int h = (g>>13)&15; int b = g>>17;
  float S = 0.f;
  float* st = ws + OFF_ST;
  const float* cdc = ws + OFF_CDC;
  for (int c=0; c<64; ++c){
    size_t idx = ((size_t)((b*64+c)*16+h)*32 + p)*256 + n;
    float v = st[idx];
    st[idx] = S;                          // emit prev
    S = fmaf(S, cdc[(b*64+c)*16 + h], v); // S = S*cd + states
  }
}

// ---------------- K6: y += exp(cum)*C@prev + D*xs -------------------------------
__global__ __launch_bounds__(256) void k6_yinter(const float* __restrict__ Dp,
                                                 float* __restrict__ ws){
  int bi = blockIdx.x;                    // (b*64+c)*16 + h
  int h = bi & 15; int bc_i = bi >> 4;
  __shared__ float sPrev[32*257];         // [p][n] pad 257
  __shared__ float sCt[128*32];           // [t][n-tile of 32]
  __shared__ float sE[128];
  size_t rb = (size_t)bc_i*128;
  const float* st   = ws + OFF_ST + (size_t)bi*8192;
  const float* cumb = ws + OFF_CUM + (size_t)bi*128;
  const float* bcp  = ws + OFF_BC;
  for (int idx = threadIdx.x; idx < 8192; idx += 256){
    int pp = idx>>8, n = idx&255;
    sPrev[pp*257+n] = st[idx];
  }
  if (threadIdx.x < 128) sE[threadIdx.x] = __expf(cumb[threadIdx.x]);
  int p = threadIdx.x & 31, tg = threadIdx.x >> 5;
  float acc[16];
  #pragma unroll
  for (int i=0;i<16;++i) acc[i]=0.f;
  for (int nt=0; nt<8; ++nt){
    int n0 = nt*32;
    __syncthreads();
    for (int idx = threadIdx.x; idx < 4096; idx += 256){
      int t = idx>>5, nl = idx&31;
      sCt[t*32+nl] = bcp[(rb+t)*512 + 256 + n0 + nl];   // C part
    }
    __syncthreads();
    #pragma unroll 4
    for (int nl=0; nl<32; ++nl){
      float pv = sPrev[p*257 + n0 + nl];
      #pragma unroll
      for (int ti=0; ti<16; ++ti)
        acc[ti] = fmaf(sCt[(tg*16+ti)*32 + nl], pv, acc[ti]);
    }
  }
  const float* xsb = ws + OFF_XS;
  float* y = ws + OFF_XBC;
  float Dh = Dp[h];
  #pragma unroll
  for (int ti=0; ti<16; ++ti){
    int t = tg*16+ti;
    size_t a = (rb+t)*512 + h*32 + p;
    y[a] = y[a] + sE[t]*acc[ti] + Dh*xsb[a];
  }
}

// ---------------- K7: gate(silu(z)) -> RMSNorm -> out_proj ----------------------
__global__ __launch_bounds__(256) void k7_final(const float* __restrict__ x,
                                                const float* __restrict__ norm_w,
                                                const float* __restrict__ Wout,
                                                float* __restrict__ ws,
                                                float* __restrict__ out){
  __shared__ float sG[8*512];
  __shared__ float sNw[512];
  __shared__ float sScale[8];
  int r0 = blockIdx.x*8;
  const float* y = ws + OFF_XBC;
  const float* M = ws + OFF_M; const float* Cc = ws + OFF_C;
  for (int i = threadIdx.x; i < 512; i += 256) sNw[i] = norm_w[i];
  for (int idx = threadIdx.x; idx < 4096; idx += 256){
    int r = idx>>9, i = idx&511;
    int row = r0 + r; int b = row>>13, l = row & 8191;
    int hh, wv;
    if (l < 4096){ hh = l>>6; wv = l&63; }
    else { int l2 = l-4096; hh = 63-(l2>>6); wv = 63-(l2&63); }
    const float* xb = x + (size_t)b*3*4096;
    float x0 = xb[hh*64+wv], x1 = xb[4096+hh*64+wv], x2 = xb[8192+hh*64+wv];
    float z = Cc[i];
    z = fmaf(x0, M[i], z);
    z = fmaf(x1, M[DPROJ+i], z);
    z = fmaf(x2, M[2*DPROJ+i], z);
    float g = y[(size_t)row*512 + i] * z * sigm(z);
    sG[idx] = g;
  }
  __syncthreads();
  int wvi = threadIdx.x >> 6, lane = threadIdx.x & 63;
  for (int rr = wvi*2; rr < wvi*2+2; ++rr){
    float s = 0.f;
    for (int i = lane; i < 512; i += 64){ float g = sG[rr*512+i]; s = fmaf(g,g,s); }
    #pragma unroll
    for (int off=32; off; off>>=1) s += __shfl_down(s, off, 64);
    if (lane==0) sScale[rr] = rsqrtf(s*(1.f/512.f) + 1e-5f);
  }
  __syncthreads();
  for (int idx = threadIdx.x; idx < 4096; idx += 256) sG[idx] *= sNw[idx & 511];
  __syncthreads();
  int d = threadIdx.x & 127, rg = threadIdx.x >> 7;
  float acc[4] = {0.f,0.f,0.f,0.f};
  for (int i=0;i<512;++i){
    float wv2 = Wout[(size_t)i*128 + d];
    #pragma unroll
    for (int q=0;q<4;++q)
      acc[q] = fmaf(sG[(rg*4+q)*512 + i], wv2, acc[q]);
  }
  #pragma unroll
  for (int q=0;q<4;++q){
    int r = rg*4+q;
    out[(size_t)(r0+r)*128 + d] = acc[q]*sScale[r];
  }
}

extern "C" void kernel_launch(void* const* d_in, const int* in_sizes, int n_in,
                              void* d_out, int out_size, void* d_ws, size_t ws_size,
                              hipStream_t stream) {
  const float* x         = (const float*)d_in[0];
  const float* fc0_w     = (const float*)d_in[1];
  const float* fc0_b     = (const float*)d_in[2];
  const float* in_proj_w = (const float*)d_in[3];
  const float* conv_w    = (const float*)d_in[4];
  const float* conv_b    = (const float*)d_in[5];
  const float* dt_bias   = (const float*)d_in[6];
  const float* A_log     = (const float*)d_in[7];
  const float* Dp        = (const float*)d_in[8];
  const float* norm_w    = (const float*)d_in[9];
  const float* out_proj_w= (const float*)d_in[10];
  float* ws  = (float*)d_ws;
  float* out = (float*)d_out;

  hipLaunchKernelGGL(k0_prep, dim3(7),     dim3(256), 0, stream, fc0_w, fc0_b, in_proj_w, ws);
  hipLaunchKernelGGL(k1_proj, dim3(16384), dim3(256), 0, stream, x, dt_bias, ws);
  hipLaunchKernelGGL(k2_conv, dim3(16384), dim3(256), 0, stream, conv_w, conv_b, ws);
  hipLaunchKernelGGL(k3_cum,  dim3(2048),  dim3(128), 0, stream, A_log, ws);
  hipLaunchKernelGGL(k4a_cb,  dim3(256),   dim3(256), 0, stream, ws);
  hipLaunchKernelGGL(k4b_intra_states, dim3(2048), dim3(256), 0, stream, ws);
  hipLaunchKernelGGL(k5_scan, dim3(1024),  dim3(256), 0, stream, ws);
  hipLaunchKernelGGL(k6_yinter, dim3(2048), dim3(256), 0, stream, Dp, ws);
  hipLaunchKernelGGL(k7_final, dim3(2048), dim3(256), 0, stream, x, norm_w, out_proj_w, ws, out);
}

// Round 2
// 267.431 us; speedup vs baseline: 2.2220x; 2.2220x over previous
//
#include <hip/hip_runtime.h>

typedef short short8 __attribute__((ext_vector_type(8)));
typedef float f32x4 __attribute__((ext_vector_type(4)));
typedef unsigned short ushort;
typedef unsigned int uint;

#define MFMA16(a,b,c) __builtin_amdgcn_mfma_f32_16x16x32_bf16(a,b,c,0,0,0)
#define DPROJ 1552

// ---- workspace byte offsets ----
constexpr size_t OFF_M    = 0;                         // 3*1552 f32
constexpr size_t OFF_CB_B = 0x5000;                    // 1552 f32
constexpr size_t OFF_WT   = 0x8000;                    // 128*512 bf16 (WoutT * norm_w)
constexpr size_t OFF_XPRE = 0x30000;                   // 16384*1024 bf16
constexpr size_t OFF_DT   = OFF_XPRE + 33554432ull;    // 16384*16 f32
constexpr size_t OFF_XS   = OFF_DT   + 1048576ull;     // 16384*512 bf16
constexpr size_t OFF_BCM  = OFF_XS   + 16777216ull;    // 16384*512 bf16  [B(256)|C(256)]
constexpr size_t OFF_CUM  = OFF_BCM  + 16777216ull;    // 2048*128 f32
constexpr size_t OFF_CDC  = OFF_CUM  + 1048576ull;     // 2048 f32
constexpr size_t OFF_CBT  = OFF_CDC  + 8192ull;        // 128*(128*128) bf16 [t][s]
constexpr size_t OFF_BT   = OFF_CBT  + 4194304ull;     // 128*(256*128) bf16 [n][s]
constexpr size_t OFF_ST   = OFF_BT   + 8388608ull;     // 2048*(32*256) bf16 [p][n]
constexpr size_t OFF_Y    = OFF_ST   + 33554432ull;    // 16384*512 f32
// end ~149 MB

__device__ __forceinline__ float sigm(float x){ return 1.0f/(1.0f + __expf(-x)); }
__device__ __forceinline__ ushort f2bf(float f){
  union { float f; uint u; } c; c.f = f;
  uint u = c.u;
  return (ushort)((u + 0x7FFFu + ((u>>16)&1u)) >> 16);
}
__device__ __forceinline__ float bf2f(ushort h){
  union { uint u; float f; } c; c.u = ((uint)h)<<16;
  return c.f;
}

// ---------------- K0: fuse fc0 into in_proj ----------------
__global__ __launch_bounds__(256) void k0_prep(const float* __restrict__ fc0_w,
                                               const float* __restrict__ fc0_b,
                                               const float* __restrict__ W,
                                               char* __restrict__ wsb){
  float* Mo = (float*)(wsb + OFF_M);
  float* Co = (float*)(wsb + OFF_CB_B);
  int j = blockIdx.x*256 + threadIdx.x;
  if (j >= DPROJ) return;
  float m0=0.f,m1=0.f,m2=0.f,cc=0.f;
  for (int d=0; d<128; ++d){
    float w = W[(size_t)d*DPROJ + j];
    m0 = fmaf(fc0_w[d],     w, m0);
    m1 = fmaf(fc0_w[128+d], w, m1);
    m2 = fmaf(fc0_w[256+d], w, m2);
    cc = fmaf(fc0_b[d],     w, cc);
  }
  Mo[j] = m0; Mo[DPROJ + j] = m1; Mo[2*DPROJ + j] = m2;
  Co[j] = cc;
}

// ---------------- K0b: WoutT'[d][i] = norm_w[i]*Wout[i][d]  (bf16) --------------
__global__ __launch_bounds__(256) void k0b_wt(const float* __restrict__ norm_w,
                                              const float* __restrict__ Wout,
                                              char* __restrict__ wsb){
  ushort* WT = (ushort*)(wsb + OFF_WT);
  int d = blockIdx.x;
  for (int i = threadIdx.x; i < 512; i += 256)
    WT[(size_t)d*512 + i] = f2bf(norm_w[i]*Wout[(size_t)i*128 + d]);
}

// ---------------- K1: gather pixel, project to xBC(1024 bf16) + dt(16 f32) ------
__global__ __launch_bounds__(256) void k1_proj(const float* __restrict__ x,
                                               const float* __restrict__ dt_bias,
                                               char* __restrict__ wsb){
  int r = blockIdx.x; int b = r>>13; int l = r & 8191;
  int h, w;
  if (l < 4096){ h = l>>6; w = l&63; }
  else { int l2 = l-4096; h = 63-(l2>>6); w = 63-(l2&63); }
  const float* xb = x + (size_t)b*3*4096;
  float x0 = xb[h*64+w], x1 = xb[4096 + h*64+w], x2 = xb[8192 + h*64+w];
  const float* M  = (const float*)(wsb + OFF_M);
  const float* Cc = (const float*)(wsb + OFF_CB_B);
  ushort* xbc = (ushort*)(wsb + OFF_XPRE) + (size_t)r*1024;
  float*  dtp = (float*)(wsb + OFF_DT) + (size_t)r*16;
  for (int j = 512 + threadIdx.x; j < DPROJ; j += 256){
    float v = Cc[j];
    v = fmaf(x0, M[j], v);
    v = fmaf(x1, M[DPROJ+j], v);
    v = fmaf(x2, M[2*DPROJ+j], v);
    if (j < 1536) xbc[j-512] = f2bf(v);
    else {
      int hh = j - 1536;
      float t = v + dt_bias[hh];
      dtp[hh] = (t > 20.f) ? t : log1pf(__expf(t));
    }
  }
}

// ---------------- K2: depthwise causal conv(4) + silu -> xs / BC (bf16) ---------
__global__ __launch_bounds__(256) void k2_conv(const float* __restrict__ conv_w,
                                               const float* __restrict__ conv_b,
                                               char* __restrict__ wsb){
  int r = blockIdx.x; int b = r>>13; int l = r & 8191;
  const ushort* xbc = (const ushort*)(wsb + OFF_XPRE);
  ushort* xs = (ushort*)(wsb + OFF_XS);
  ushort* bc = (ushort*)(wsb + OFF_BCM);
  size_t rowb = (size_t)b*8192;
  for (int ch = threadIdx.x; ch < 1024; ch += 256){
    float acc = conv_b[ch];
    #pragma unroll
    for (int k=0;k<4;++k){
      int li = l-3+k;
      if (li >= 0) acc = fmaf(bf2f(xbc[(rowb+li)*1024 + ch]), conv_w[ch*4+k], acc);
    }
    float v = acc * sigm(acc);
    if (ch < 512) xs[(size_t)r*512 + ch] = f2bf(v);
    else          bc[(size_t)r*512 + (ch-512)] = f2bf(v);
  }
}

// ---------------- K3: per (b,c,h) inclusive cumsum of dt*A ----------------------
__global__ __launch_bounds__(128) void k3_cum(const float* __restrict__ A_log,
                                              char* __restrict__ wsb){
  int bi = blockIdx.x;                    // (b*64+c)*16 + h
  int h = bi & 15;
  int t = threadIdx.x;
  __shared__ float s[128];
  float A = -__expf(A_log[h]);
  const float* dtp = (const float*)(wsb + OFF_DT);
  size_t row = (size_t)(bi>>4)*128 + t;
  float a = dtp[row*16 + h] * A;
  s[t] = a; __syncthreads();
  for (int off=1; off<128; off<<=1){
    float v = (t>=off) ? s[t-off] : 0.f;
    __syncthreads();
    s[t] += v;
    __syncthreads();
  }
  ((float*)(wsb + OFF_CUM))[(size_t)bi*128 + t] = s[t];
  if (t==127) ((float*)(wsb + OFF_CDC))[bi] = __expf(s[127]);
}

// ---------------- K4a: CB[t][s] = sum_n C[t,n]B[s,n]  via MFMA ------------------
__global__ __launch_bounds__(256) void k4a_cb(char* __restrict__ wsb){
  int bi = blockIdx.x;                    // (b*64+c)*4 + squad
  int sq = bi & 3; int bc = bi >> 2;
  __shared__ __align__(16) char sC[16384];   // C[128][64] bf16 swizzled rows(128B)
  __shared__ __align__(16) char sB[4096];    // B[32][64]  bf16 swizzled
  const ushort* bcm = (const ushort*)(wsb + OFF_BCM);
  ushort* cbt = (ushort*)(wsb + OFF_CBT) + (size_t)bc*16384;
  size_t rb = (size_t)bc*128;
  int tid = threadIdx.x;
  int lane = tid&63, wid = tid>>6, l15 = lane&15, l4 = lane>>4;
  int s_base = sq*32;
  f32x4 acc[2][2] = {};
  for (int nt = 0; nt < 4; ++nt){
    int n0 = nt*64;
    __syncthreads();
    for (int idx = tid; idx < 1024; idx += 256){
      int t = idx>>3, c = idx&7;
      uint4 v = *(const uint4*)(bcm + (rb+t)*512 + 256 + n0 + c*8);
      *(uint4*)(sC + ((t*128 + c*16) ^ ((t&7)<<4))) = v;
    }
    {
      int idx = tid;  // exactly 256 chunks
      int s = idx>>3, c = idx&7;
      uint4 v = *(const uint4*)(bcm + (rb+s_base+s)*512 + n0 + c*8);
      *(uint4*)(sB + ((s*128 + c*16) ^ ((s&7)<<4))) = v;
    }
    __syncthreads();
    #pragma unroll
    for (int ks = 0; ks < 2; ++ks){
      int kb = ks*64 + l4*16;
      int t0 = wid*32 + l15, t1 = t0 + 16;
      short8 a0 = *(const short8*)(sC + ((t0*128 + kb) ^ ((t0&7)<<4)));
      short8 a1 = *(const short8*)(sC + ((t1*128 + kb) ^ ((t1&7)<<4)));
      short8 b0 = *(const short8*)(sB + ((l15*128 + kb) ^ ((l15&7)<<4)));
      short8 b1 = *(const short8*)(sB + (((16+l15)*128 + kb) ^ (((16+l15)&7)<<4)));
      acc[0][0] = MFMA16(a0,b0,acc[0][0]);
      acc[0][1] = MFMA16(a0,b1,acc[0][1]);
      acc[1][0] = MFMA16(a1,b0,acc[1][0]);
      acc[1][1] = MFMA16(a1,b1,acc[1][1]);
    }
  }
  #pragma unroll
  for (int mt=0; mt<2; ++mt)
  #pragma unroll
  for (int st=0; st<2; ++st)
  #pragma unroll
  for (int r=0; r<4; ++r){
    int t = wid*32 + mt*16 + l4*4 + r;
    int s = s_base + st*16 + l15;
    cbt[t*128 + s] = f2bf(acc[mt][st][r]);
  }
}

// ---------------- K4t: Bt[n][s] transpose (per b,c) -----------------------------
__global__ __launch_bounds__(256) void k4t_bt(char* __restrict__ wsb){
  int bc = blockIdx.x; int n = threadIdx.x;
  const ushort* bcm = (const ushort*)(wsb + OFF_BCM);
  size_t rb = (size_t)bc*128;
  uint pk[64];
  #pragma unroll
  for (int s2 = 0; s2 < 64; ++s2){
    uint lo = bcm[(rb + 2*s2  )*512 + n];
    uint hi = bcm[(rb + 2*s2+1)*512 + n];
    pk[s2] = lo | (hi<<16);
  }
  uint4* out = (uint4*)((ushort*)(wsb + OFF_BT) + (size_t)bc*32768 + (size_t)n*128);
  #pragma unroll
  for (int k=0;k<16;++k){
    uint4 v; v.x = pk[4*k]; v.y = pk[4*k+1]; v.z = pk[4*k+2]; v.w = pk[4*k+3];
    out[k] = v;
  }
}

// -------- K4b: per (b,c,h): attn build + y_intra MFMA + states MFMA -------------
__global__ __launch_bounds__(256) void k4b_intra_states(char* __restrict__ wsb){
  int bi = blockIdx.x;                    // (b*64+c)*16 + h
  int h = bi & 15; int bc = bi >> 4;
  __shared__ __align__(16) char sAttn[32768];  // [t][s] bf16, rows 256B, swizzled
  __shared__ __align__(16) char sXT[8192];     // [p][s] bf16
  __shared__ __align__(16) char sXW[8192];     // [p][s]*w[s] bf16
  __shared__ float sCum[128], sDt[128], sW[128];
  const ushort* cbt = (const ushort*)(wsb + OFF_CBT) + (size_t)bc*16384;
  const ushort* xs  = (const ushort*)(wsb + OFF_XS);
  const ushort* bt  = (const ushort*)(wsb + OFF_BT) + (size_t)bc*32768;
  const float* cum  = (const float*)(wsb + OFF_CUM) + (size_t)bi*128;
  const float* dtp  = (const float*)(wsb + OFF_DT);
  float* Y = (float*)(wsb + OFF_Y);
  ushort* st = (ushort*)(wsb + OFF_ST) + (size_t)bi*8192;
  size_t rb = (size_t)bc*128;
  int tid = threadIdx.x;
  // stage CB
  for (int idx = tid; idx < 2048; idx += 256){
    int t = idx>>4, c = idx&15;
    uint4 v = *(const uint4*)(cbt + t*128 + c*8);
    *(uint4*)(sAttn + ((t*256 + c*16) ^ ((t&7)<<4))) = v;
  }
  // stage x transposed
  for (int idx = tid; idx < 4096; idx += 256){
    int s = idx>>5, p = idx&31;
    ushort v = xs[(rb+s)*512 + h*32 + p];
    *(ushort*)(sXT + ((p*256 + s*2) ^ ((p&7)<<4))) = v;
  }
  if (tid < 128){ sCum[tid] = cum[tid]; sDt[tid] = dtp[(rb+tid)*16 + h]; }
  __syncthreads();
  if (tid < 128) sW[tid] = __expf(sCum[127] - sCum[tid]) * sDt[tid];
  __syncthreads();
  // attn in-place transform
  for (int idx = tid; idx < 16384; idx += 256){
    int t = idx>>7, s = idx&127;
    ushort* a = (ushort*)(sAttn + ((t*256 + s*2) ^ ((t&7)<<4)));
    float v = 0.f;
    if (t >= s) v = bf2f(*a) * __expf(sCum[t]-sCum[s]) * sDt[s];
    *a = f2bf(v);
  }
  // xw = xT * w[s]
  for (int idx = tid; idx < 4096; idx += 256){
    int p = idx>>7, s = idx&127;
    ushort v = *(const ushort*)(sXT + ((p*256 + s*2) ^ ((p&7)<<4)));
    *(ushort*)(sXW + ((p*256 + s*2) ^ ((p&7)<<4))) = f2bf(bf2f(v)*sW[s]);
  }
  __syncthreads();
  int lane = tid&63, wid = tid>>6, l15 = lane&15, l4 = lane>>4;
  // ---- y_intra = attn @ x : M=t(128), N=p(32), K=s(128) ----
  f32x4 acc[2][2] = {};
  #pragma unroll
  for (int ks = 0; ks < 4; ++ks){
    int kb = ks*64 + l4*16;
    int t0 = wid*32 + l15, t1 = t0+16;
    short8 a0 = *(const short8*)(sAttn + ((t0*256 + kb) ^ ((t0&7)<<4)));
    short8 a1 = *(const short8*)(sAttn + ((t1*256 + kb) ^ ((t1&7)<<4)));
    short8 b0 = *(const short8*)(sXT + ((l15*256 + kb) ^ ((l15&7)<<4)));
    short8 b1 = *(const short8*)(sXT + (((16+l15)*256 + kb) ^ (((16+l15)&7)<<4)));
    acc[0][0] = MFMA16(a0,b0,acc[0][0]);
    acc[0][1] = MFMA16(a0,b1,acc[0][1]);
    acc[1][0] = MFMA16(a1,b0,acc[1][0]);
    acc[1][1] = MFMA16(a1,b1,acc[1][1]);
  }
  #pragma unroll
  for (int mt=0; mt<2; ++mt)
  #pragma unroll
  for (int nt=0; nt<2; ++nt)
  #pragma unroll
  for (int r=0; r<4; ++r){
    int t = wid*32 + mt*16 + l4*4 + r;
    int p = nt*16 + l15;
    Y[(rb+t)*512 + h*32 + p] = acc[mt][nt][r];
  }
  // ---- states = xw @ B : M=p(32), N=n(256), K=s(128) ----
  f32x4 acc2[2][4] = {};
  #pragma unroll
  for (int ks = 0; ks < 4; ++ks){
    int kb = ks*64 + l4*16;
    short8 a0 = *(const short8*)(sXW + ((l15*256 + kb) ^ ((l15&7)<<4)));
    short8 a1 = *(const short8*)(sXW + (((16+l15)*256 + kb) ^ (((16+l15)&7)<<4)));
    #pragma unroll
    for (int ntl = 0; ntl < 4; ++ntl){
      int n = wid*64 + ntl*16 + l15;
      short8 b = *(const short8*)(bt + (size_t)n*128 + ks*32 + l4*8);
      acc2[0][ntl] = MFMA16(a0,b,acc2[0][ntl]);
      acc2[1][ntl] = MFMA16(a1,b,acc2[1][ntl]);
    }
  }
  #pragma unroll
  for (int mt=0; mt<2; ++mt)
  #pragma unroll
  for (int ntl=0; ntl<4; ++ntl)
  #pragma unroll
  for (int r=0; r<4; ++r){
    int p = mt*16 + l4*4 + r;
    int n = wid*64 + ntl*16 + l15;
    st[p*256 + n] = f2bf(acc2[mt][ntl][r]);
  }
}

// ---------------- K5: sequential chunk scan (bf16 in place) ---------------------
__global__ __launch_bounds__(256) void k5_scan(char* __restrict__ wsb){
  int g = blockIdx.x*256 + threadIdx.x;   // 262144 threads
  int n = g & 255; int p = (g>>8)&31; int h = (g>>13)&15; int b = g>>17;
  ushort* st = (ushort*)(wsb + OFF_ST);
  const float* cdc = (const float*)(wsb + OFF_CDC);
  float S = 0.f;
  for (int c=0; c<64; ++c){
    int bi = (b*64+c)*16 + h;
    size_t idx = (size_t)bi*8192 + (size_t)p*256 + n;
    float v = bf2f(st[idx]);
    st[idx] = f2bf(S);
    S = fmaf(S, cdc[bi], v);
  }
}

// ---------------- K6: y += exp(cum[t]) * C@prev^T + D*xs  (MFMA, LDS-free) ------
__global__ __launch_bounds__(256) void k6_yinter(const float* __restrict__ Dp,
                                                 char* __restrict__ wsb){
  int bi = blockIdx.x;                    // (b*64+c)*16 + h
  int h = bi & 15; int bc = bi >> 4;
  __shared__ float sE[128];
  const ushort* bcm  = (const ushort*)(wsb + OFF_BCM);
  const ushort* prev = (const ushort*)(wsb + OFF_ST) + (size_t)bi*8192;
  const ushort* xs   = (const ushort*)(wsb + OFF_XS);
  const float* cum   = (const float*)(wsb + OFF_CUM) + (size_t)bi*128;
  float* Y = (float*)(wsb + OFF_Y);
  size_t rb = (size_t)bc*128;
  int tid = threadIdx.x;
  if (tid < 128) sE[tid] = __expf(cum[tid]);
  __syncthreads();
  int lane = tid&63, wid = tid>>6, l15 = lane&15, l4 = lane>>4;
  f32x4 acc[2][2] = {};
  #pragma unroll
  for (int ks = 0; ks < 8; ++ks){
    int koff = ks*32 + l4*8;
    int t0 = wid*32 + l15;
    short8 a0 = *(const short8*)(bcm + (rb+t0)*512 + 256 + koff);
    short8 a1 = *(const short8*)(bcm + (rb+t0+16)*512 + 256 + koff);
    short8 b0 = *(const short8*)(prev + (size_t)l15*256 + koff);
    short8 b1 = *(const short8*)(prev + (size_t)(16+l15)*256 + koff);
    acc[0][0] = MFMA16(a0,b0,acc[0][0]);
    acc[0][1] = MFMA16(a0,b1,acc[0][1]);
    acc[1][0] = MFMA16(a1,b0,acc[1][0]);
    acc[1][1] = MFMA16(a1,b1,acc[1][1]);
  }
  float Dh = Dp[h];
  #pragma unroll
  for (int mt=0; mt<2; ++mt)
  #pragma unroll
  for (int nt=0; nt<2; ++nt)
  #pragma unroll
  for (int r=0; r<4; ++r){
    int t = wid*32 + mt*16 + l4*4 + r;
    int p = nt*16 + l15;
    size_t a = (rb+t)*512 + h*32 + p;
    Y[a] = Y[a] + sE[t]*acc[mt][nt][r] + Dh*bf2f(xs[a]);
  }
}

// ---------------- K7: gate(silu(z)) -> RMS -> out_proj (MFMA) -------------------
__global__ __launch_bounds__(256) void k7_final(const float* __restrict__ x,
                                                char* __restrict__ wsb,
                                                float* __restrict__ out){
  int r0 = blockIdx.x*32;                  // 512 blocks
  __shared__ __align__(16) char sG[32768]; // G[32][512] bf16 rows 1024B, swizzled
  __shared__ float sScale[32];
  const float* Y  = (const float*)(wsb + OFF_Y);
  const float* M  = (const float*)(wsb + OFF_M);
  const float* Cb = (const float*)(wsb + OFF_CB_B);
  const ushort* WT = (const ushort*)(wsb + OFF_WT);
  int tid = threadIdx.x;
  int r = tid>>3, li = tid&7;
  int row = r0 + r; int b = row>>13, l = row & 8191;
  int hh, wv;
  if (l < 4096){ hh = l>>6; wv = l&63; }
  else { int l2 = l-4096; hh = 63-(l2>>6); wv = 63-(l2&63); }
  const float* xb = x + (size_t)b*12288;
  float x0 = xb[hh*64+wv], x1 = xb[4096+hh*64+wv], x2 = xb[8192+hh*64+wv];
  float sq = 0.f;
  for (int k = 0; k < 64; ++k){
    int i = li + 8*k;
    float z = Cb[i];
    z = fmaf(x0, M[i], z);
    z = fmaf(x1, M[DPROJ+i], z);
    z = fmaf(x2, M[2*DPROJ+i], z);
    float y = Y[(size_t)row*512 + i];
    float g = y * z * sigm(z);
    sq = fmaf(g, g, sq);
    *(ushort*)(sG + ((r*1024 + i*2) ^ ((r&7)<<4))) = f2bf(g);
  }
  sq += __shfl_xor(sq, 1, 64);
  sq += __shfl_xor(sq, 2, 64);
  sq += __shfl_xor(sq, 4, 64);
  if (li == 0) sScale[r] = rsqrtf(sq*(1.f/512.f) + 1e-5f);
  __syncthreads();
  int lane = tid&63, wid = tid>>6, l15 = lane&15, l4 = lane>>4;
  f32x4 acc[2][2] = {};
  #pragma unroll
  for (int ks = 0; ks < 16; ++ks){
    int kb = ks*64 + l4*16;
    int rr0 = l15, rr1 = 16+l15;
    short8 a0 = *(const short8*)(sG + ((rr0*1024 + kb) ^ ((rr0&7)<<4)));
    short8 a1 = *(const short8*)(sG + ((rr1*1024 + kb) ^ ((rr1&7)<<4)));
    int koff = ks*32 + l4*8;
    short8 b0 = *(const short8*)(WT + (size_t)(wid*32 + l15)*512 + koff);
    short8 b1 = *(const short8*)(WT + (size_t)(wid*32 + 16 + l15)*512 + koff);
    acc[0][0] = MFMA16(a0,b0,acc[0][0]);
    acc[0][1] = MFMA16(a0,b1,acc[0][1]);
    acc[1][0] = MFMA16(a1,b0,acc[1][0]);
    acc[1][1] = MFMA16(a1,b1,acc[1][1]);
  }
  #pragma unroll
  for (int mt=0; mt<2; ++mt)
  #pragma unroll
  for (int nt=0; nt<2; ++nt)
  #pragma unroll
  for (int r4=0; r4<4; ++r4){
    int rr = mt*16 + l4*4 + r4;
    int d = wid*32 + nt*16 + l15;
    out[(size_t)(r0+rr)*128 + d] = acc[mt][nt][r4] * sScale[rr];
  }
}

extern "C" void kernel_launch(void* const* d_in, const int* in_sizes, int n_in,
                              void* d_out, int out_size, void* d_ws, size_t ws_size,
                              hipStream_t stream) {
  const float* x         = (const float*)d_in[0];
  const float* fc0_w     = (const float*)d_in[1];
  const float* fc0_b     = (const float*)d_in[2];
  const float* in_proj_w = (const float*)d_in[3];
  const float* conv_w    = (const float*)d_in[4];
  const float* conv_b    = (const float*)d_in[5];
  const float* dt_bias   = (const float*)d_in[6];
  const float* A_log     = (const float*)d_in[7];
  const float* Dp        = (const float*)d_in[8];
  const float* norm_w    = (const float*)d_in[9];
  const float* out_proj_w= (const float*)d_in[10];
  char* wsb  = (char*)d_ws;
  float* out = (float*)d_out;

  k0_prep<<<dim3(7),     dim3(256), 0, stream>>>(fc0_w, fc0_b, in_proj_w, wsb);
  k0b_wt <<<dim3(128),   dim3(256), 0, stream>>>(norm_w, out_proj_w, wsb);
  k1_proj<<<dim3(16384), dim3(256), 0, stream>>>(x, dt_bias, wsb);
  k2_conv<<<dim3(16384), dim3(256), 0, stream>>>(conv_w, conv_b, wsb);
  k3_cum <<<dim3(2048),  dim3(128), 0, stream>>>(A_log, wsb);
  k4a_cb <<<dim3(512),   dim3(256), 0, stream>>>(wsb);
  k4t_bt <<<dim3(128),   dim3(256), 0, stream>>>(wsb);
  k4b_intra_states<<<dim3(2048), dim3(256), 0, stream>>>(wsb);
  k5_scan<<<dim3(1024),  dim3(256), 0, stream>>>(wsb);
  k6_yinter<<<dim3(2048), dim3(256), 0, stream>>>(Dp, wsb);
  k7_final<<<dim3(512),  dim3(256), 0, stream>>>(x, wsb, out);
}

// Round 3
// 203.145 us; speedup vs baseline: 2.9251x; 1.3165x over previous
//
#include <hip/hip_runtime.h>

typedef short short8 __attribute__((ext_vector_type(8)));
typedef float f32x4 __attribute__((ext_vector_type(4)));
typedef unsigned short ushort;
typedef unsigned int uint;

#define MFMA16(a,b,c) __builtin_amdgcn_mfma_f32_16x16x32_bf16(a,b,c,0,0,0)
#define DPROJ 1552

// ---- workspace byte offsets ----
constexpr size_t OFF_M    = 0;                         // 3*1552 f32
constexpr size_t OFF_CB_B = 0x5000;                    // 1552 f32
constexpr size_t OFF_WT   = 0x8000;                    // 128*512 bf16 (WoutT * norm_w)
constexpr size_t OFF_XPRE = 0x30000;                   // (unused now)
constexpr size_t OFF_DT   = OFF_XPRE + 33554432ull;    // 16384*16 f32
constexpr size_t OFF_XS   = OFF_DT   + 1048576ull;     // 16384*512 bf16
constexpr size_t OFF_BCM  = OFF_XS   + 16777216ull;    // 16384*512 bf16  [B(256)|C(256)]
constexpr size_t OFF_CUM  = OFF_BCM  + 16777216ull;    // 2048*128 f32
constexpr size_t OFF_CDC  = OFF_CUM  + 1048576ull;     // 2048 f32
constexpr size_t OFF_CBT  = OFF_CDC  + 8192ull;        // 128*(128*128) bf16 [t][s]
constexpr size_t OFF_BT   = OFF_CBT  + 4194304ull;     // 128*(256*128) bf16 [n][s]
constexpr size_t OFF_ST   = OFF_BT   + 8388608ull;     // 2048*(32*256) bf16 [p][n]
constexpr size_t OFF_Y    = OFF_ST   + 33554432ull;    // 16384*512 f32
// end ~149 MB

__device__ __forceinline__ float sigm(float x){ return 1.0f/(1.0f + __expf(-x)); }
__device__ __forceinline__ ushort f2bf(float f){
  union { float f; uint u; } c; c.f = f;
  uint u = c.u;
  return (ushort)((u + 0x7FFFu + ((u>>16)&1u)) >> 16);
}
__device__ __forceinline__ float bf2f(ushort h){
  union { uint u; float f; } c; c.u = ((uint)h)<<16;
  return c.f;
}

// ---------------- K0: fuse fc0 into in_proj ----------------
__global__ __launch_bounds__(256) void k0_prep(const float* __restrict__ fc0_w,
                                               const float* __restrict__ fc0_b,
                                               const float* __restrict__ W,
                                               char* __restrict__ wsb){
  float* Mo = (float*)(wsb + OFF_M);
  float* Co = (float*)(wsb + OFF_CB_B);
  int j = blockIdx.x*256 + threadIdx.x;
  if (j >= DPROJ) return;
  float m0=0.f,m1=0.f,m2=0.f,cc=0.f;
  for (int d=0; d<128; ++d){
    float w = W[(size_t)d*DPROJ + j];
    m0 = fmaf(fc0_w[d],     w, m0);
    m1 = fmaf(fc0_w[128+d], w, m1);
    m2 = fmaf(fc0_w[256+d], w, m2);
    cc = fmaf(fc0_b[d],     w, cc);
  }
  Mo[j] = m0; Mo[DPROJ + j] = m1; Mo[2*DPROJ + j] = m2;
  Co[j] = cc;
}

// ---------------- K0b: WoutT'[d][i] = norm_w[i]*Wout[i][d]  (bf16) --------------
__global__ __launch_bounds__(256) void k0b_wt(const float* __restrict__ norm_w,
                                              const float* __restrict__ Wout,
                                              char* __restrict__ wsb){
  ushort* WT = (ushort*)(wsb + OFF_WT);
  int d = blockIdx.x;
  for (int i = threadIdx.x; i < 512; i += 256)
    WT[(size_t)d*512 + i] = f2bf(norm_w[i]*Wout[(size_t)i*128 + d]);
}

// ---------------- K1dt: dt = softplus(proj + bias) ------------------------------
__global__ __launch_bounds__(256) void k1dt(const float* __restrict__ x,
                                            const float* __restrict__ dt_bias,
                                            char* __restrict__ wsb){
  int idx = blockIdx.x*256 + threadIdx.x;   // 262144
  int r = idx >> 4, hh = idx & 15;
  int b = r >> 13, l = r & 8191;
  int hp, wv;
  if (l < 4096){ hp = l>>6; wv = l&63; }
  else { int l2 = l-4096; hp = 63-(l2>>6); wv = 63-(l2&63); }
  const float* xb = x + (size_t)b*12288;
  float x0 = xb[hp*64+wv], x1 = xb[4096+hp*64+wv], x2 = xb[8192+hp*64+wv];
  const float* M  = (const float*)(wsb + OFF_M);
  const float* Cc = (const float*)(wsb + OFF_CB_B);
  int j = 1536 + hh;
  float v = Cc[j];
  v = fmaf(x0, M[j], v);
  v = fmaf(x1, M[DPROJ+j], v);
  v = fmaf(x2, M[2*DPROJ+j], v);
  float t = v + dt_bias[hh];
  ((float*)(wsb+OFF_DT))[(size_t)r*16+hh] = (t > 20.f) ? t : log1pf(__expf(t));
}

// ------ K12: fused proj+causal conv(4)+silu -> xs / BC (no xbc intermediate) ----
__device__ __forceinline__ void proj8(int li, const float* __restrict__ xb,
                                      const float* m0, const float* m1, const float* m2,
                                      const float* c8, float* dst){
  if (li < 0){
    #pragma unroll
    for (int j=0;j<8;++j) dst[j] = 0.f;
    return;
  }
  int hh, wv;
  if (li < 4096){ hh = li>>6; wv = li&63; }
  else { int l2 = li-4096; hh = 63-(l2>>6); wv = 63-(l2&63); }
  float x0 = xb[hh*64+wv], x1 = xb[4096+hh*64+wv], x2 = xb[8192+hh*64+wv];
  #pragma unroll
  for (int j=0;j<8;++j)
    dst[j] = fmaf(x2, m2[j], fmaf(x1, m1[j], fmaf(x0, m0[j], c8[j])));
}

__device__ __forceinline__ void emit8(ushort* __restrict__ outp, size_t row,
                                      const float* cb8, const float* cw0, const float* cw1,
                                      const float* cw2, const float* cw3,
                                      const float* wA, const float* wB,
                                      const float* wC, const float* wD){
  ushort o[8];
  #pragma unroll
  for (int j=0;j<8;++j){
    float a = cb8[j];
    a = fmaf(wA[j], cw0[j], a);
    a = fmaf(wB[j], cw1[j], a);
    a = fmaf(wC[j], cw2[j], a);
    a = fmaf(wD[j], cw3[j], a);
    o[j] = f2bf(a * sigm(a));
  }
  *(uint4*)(outp + row*512) = *(uint4*)o;
}

__global__ __launch_bounds__(256) void k12_projconv(const float* __restrict__ x,
                                                    const float* __restrict__ conv_w,
                                                    const float* __restrict__ conv_b,
                                                    char* __restrict__ wsb){
  int tid = threadIdx.x;
  int cg = tid & 127, rl = tid >> 7;
  int row0 = blockIdx.x*16 + rl*8;        // 1024 blocks, 16 rows each
  int b = row0 >> 13, l0 = row0 & 8191;
  const float* M  = (const float*)(wsb + OFF_M);
  const float* Cc = (const float*)(wsb + OFF_CB_B);
  const float* xb = x + (size_t)b*12288;
  int ch0 = cg*8, j0 = 512 + ch0;
  float m0[8],m1[8],m2[8],c8[8],cw0[8],cw1[8],cw2[8],cw3[8],cb8[8];
  #pragma unroll
  for (int j=0;j<8;++j){
    m0[j]=M[j0+j]; m1[j]=M[DPROJ+j0+j]; m2[j]=M[2*DPROJ+j0+j]; c8[j]=Cc[j0+j];
    cw0[j]=conv_w[(ch0+j)*4+0]; cw1[j]=conv_w[(ch0+j)*4+1];
    cw2[j]=conv_w[(ch0+j)*4+2]; cw3[j]=conv_w[(ch0+j)*4+3];
    cb8[j]=conv_b[ch0+j];
  }
  ushort* outp = (ch0 < 512) ? ((ushort*)(wsb+OFF_XS) + ch0)
                             : ((ushort*)(wsb+OFF_BCM) + (ch0-512));
  float w0[8],w1[8],w2[8],w3[8];
  proj8(l0-3, xb, m0,m1,m2,c8, w1);
  proj8(l0-2, xb, m0,m1,m2,c8, w2);
  proj8(l0-1, xb, m0,m1,m2,c8, w3);
  #pragma unroll
  for (int it=0; it<2; ++it){
    int l = l0 + it*4;
    size_t r = (size_t)row0 + it*4;
    proj8(l,   xb, m0,m1,m2,c8, w0); emit8(outp, r,   cb8,cw0,cw1,cw2,cw3, w1,w2,w3,w0);
    proj8(l+1, xb, m0,m1,m2,c8, w1); emit8(outp, r+1, cb8,cw0,cw1,cw2,cw3, w2,w3,w0,w1);
    proj8(l+2, xb, m0,m1,m2,c8, w2); emit8(outp, r+2, cb8,cw0,cw1,cw2,cw3, w3,w0,w1,w2);
    proj8(l+3, xb, m0,m1,m2,c8, w3); emit8(outp, r+3, cb8,cw0,cw1,cw2,cw3, w0,w1,w2,w3);
  }
}

// ---------------- K3: per (b,c,h) inclusive cumsum of dt*A ----------------------
__global__ __launch_bounds__(128) void k3_cum(const float* __restrict__ A_log,
                                              char* __restrict__ wsb){
  int bi = blockIdx.x;                    // (b*64+c)*16 + h
  int h = bi & 15;
  int t = threadIdx.x;
  __shared__ float s[128];
  float A = -__expf(A_log[h]);
  const float* dtp = (const float*)(wsb + OFF_DT);
  size_t row = (size_t)(bi>>4)*128 + t;
  float a = dtp[row*16 + h] * A;
  s[t] = a; __syncthreads();
  for (int off=1; off<128; off<<=1){
    float v = (t>=off) ? s[t-off] : 0.f;
    __syncthreads();
    s[t] += v;
    __syncthreads();
  }
  ((float*)(wsb + OFF_CUM))[(size_t)bi*128 + t] = s[t];
  if (t==127) ((float*)(wsb + OFF_CDC))[bi] = __expf(s[127]);
}

// ---------------- K4a: CB[t][s] = sum_n C[t,n]B[s,n]  via MFMA ------------------
__global__ __launch_bounds__(256) void k4a_cb(char* __restrict__ wsb){
  int bi = blockIdx.x;                    // (b*64+c)*4 + squad
  int sq = bi & 3; int bc = bi >> 2;
  __shared__ __align__(16) char sC[16384];   // C[128][64] bf16 swizzled rows(128B)
  __shared__ __align__(16) char sB[4096];    // B[32][64]  bf16 swizzled
  const ushort* bcm = (const ushort*)(wsb + OFF_BCM);
  ushort* cbt = (ushort*)(wsb + OFF_CBT) + (size_t)bc*16384;
  size_t rb = (size_t)bc*128;
  int tid = threadIdx.x;
  int lane = tid&63, wid = tid>>6, l15 = lane&15, l4 = lane>>4;
  int s_base = sq*32;
  f32x4 acc[2][2] = {};
  for (int nt = 0; nt < 4; ++nt){
    int n0 = nt*64;
    __syncthreads();
    for (int idx = tid; idx < 1024; idx += 256){
      int t = idx>>3, c = idx&7;
      uint4 v = *(const uint4*)(bcm + (rb+t)*512 + 256 + n0 + c*8);
      *(uint4*)(sC + ((t*128 + c*16) ^ ((t&7)<<4))) = v;
    }
    {
      int idx = tid;  // exactly 256 chunks
      int s = idx>>3, c = idx&7;
      uint4 v = *(const uint4*)(bcm + (rb+s_base+s)*512 + n0 + c*8);
      *(uint4*)(sB + ((s*128 + c*16) ^ ((s&7)<<4))) = v;
    }
    __syncthreads();
    #pragma unroll
    for (int ks = 0; ks < 2; ++ks){
      int kb = ks*64 + l4*16;
      int t0 = wid*32 + l15, t1 = t0 + 16;
      short8 a0 = *(const short8*)(sC + ((t0*128 + kb) ^ ((t0&7)<<4)));
      short8 a1 = *(const short8*)(sC + ((t1*128 + kb) ^ ((t1&7)<<4)));
      short8 b0 = *(const short8*)(sB + ((l15*128 + kb) ^ ((l15&7)<<4)));
      short8 b1 = *(const short8*)(sB + (((16+l15)*128 + kb) ^ (((16+l15)&7)<<4)));
      acc[0][0] = MFMA16(a0,b0,acc[0][0]);
      acc[0][1] = MFMA16(a0,b1,acc[0][1]);
      acc[1][0] = MFMA16(a1,b0,acc[1][0]);
      acc[1][1] = MFMA16(a1,b1,acc[1][1]);
    }
  }
  #pragma unroll
  for (int mt=0; mt<2; ++mt)
  #pragma unroll
  for (int st=0; st<2; ++st)
  #pragma unroll
  for (int r=0; r<4; ++r){
    int t = wid*32 + mt*16 + l4*4 + r;
    int s = s_base + st*16 + l15;
    cbt[t*128 + s] = f2bf(acc[mt][st][r]);
  }
}

// ---------------- K4t: Bt[n][s] transpose (per b,c) -----------------------------
__global__ __launch_bounds__(256) void k4t_bt(char* __restrict__ wsb){
  int bc = blockIdx.x; int n = threadIdx.x;
  const ushort* bcm = (const ushort*)(wsb + OFF_BCM);
  size_t rb = (size_t)bc*128;
  uint pk[64];
  #pragma unroll
  for (int s2 = 0; s2 < 64; ++s2){
    uint lo = bcm[(rb + 2*s2  )*512 + n];
    uint hi = bcm[(rb + 2*s2+1)*512 + n];
    pk[s2] = lo | (hi<<16);
  }
  uint4* out = (uint4*)((ushort*)(wsb + OFF_BT) + (size_t)bc*32768 + (size_t)n*128);
  #pragma unroll
  for (int k=0;k<16;++k){
    uint4 v; v.x = pk[4*k]; v.y = pk[4*k+1]; v.z = pk[4*k+2]; v.w = pk[4*k+3];
    out[k] = v;
  }
}

// -------- K4b: per (b,c,h): attn build + y_intra MFMA + states MFMA -------------
__global__ __launch_bounds__(256) void k4b_intra_states(char* __restrict__ wsb){
  int bi = blockIdx.x;                    // (b*64+c)*16 + h
  int h = bi & 15; int bc = bi >> 4;
  __shared__ __align__(16) char sAttn[32768];  // [t][s] bf16, rows 256B, swizzled
  __shared__ __align__(16) char sXT[8192];     // [p][s] bf16
  __shared__ __align__(16) char sXW[8192];     // [p][s]*w[s] bf16
  __shared__ float sCum[128], sDt[128], sW[128];
  const ushort* cbt = (const ushort*)(wsb + OFF_CBT) + (size_t)bc*16384;
  const ushort* xs  = (const ushort*)(wsb + OFF_XS);
  const ushort* bt  = (const ushort*)(wsb + OFF_BT) + (size_t)bc*32768;
  const float* cum  = (const float*)(wsb + OFF_CUM) + (size_t)bi*128;
  const float* dtp  = (const float*)(wsb + OFF_DT);
  float* Y = (float*)(wsb + OFF_Y);
  ushort* st = (ushort*)(wsb + OFF_ST) + (size_t)bi*8192;
  size_t rb = (size_t)bc*128;
  int tid = threadIdx.x;
  // stage CB
  for (int idx = tid; idx < 2048; idx += 256){
    int t = idx>>4, c = idx&15;
    uint4 v = *(const uint4*)(cbt + t*128 + c*8);
    *(uint4*)(sAttn + ((t*256 + c*16) ^ ((t&7)<<4))) = v;
  }
  // stage x transposed
  for (int idx = tid; idx < 4096; idx += 256){
    int s = idx>>5, p = idx&31;
    ushort v = xs[(rb+s)*512 + h*32 + p];
    *(ushort*)(sXT + ((p*256 + s*2) ^ ((p&7)<<4))) = v;
  }
  if (tid < 128){ sCum[tid] = cum[tid]; sDt[tid] = dtp[(rb+tid)*16 + h]; }
  __syncthreads();
  if (tid < 128) sW[tid] = __expf(sCum[127] - sCum[tid]) * sDt[tid];
  __syncthreads();
  // attn in-place transform
  for (int idx = tid; idx < 16384; idx += 256){
    int t = idx>>7, s = idx&127;
    ushort* a = (ushort*)(sAttn + ((t*256 + s*2) ^ ((t&7)<<4)));
    float v = 0.f;
    if (t >= s) v = bf2f(*a) * __expf(sCum[t]-sCum[s]) * sDt[s];
    *a = f2bf(v);
  }
  // xw = xT * w[s]
  for (int idx = tid; idx < 4096; idx += 256){
    int p = idx>>7, s = idx&127;
    ushort v = *(const ushort*)(sXT + ((p*256 + s*2) ^ ((p&7)<<4)));
    *(ushort*)(sXW + ((p*256 + s*2) ^ ((p&7)<<4))) = f2bf(bf2f(v)*sW[s]);
  }
  __syncthreads();
  int lane = tid&63, wid = tid>>6, l15 = lane&15, l4 = lane>>4;
  // ---- y_intra = attn @ x : M=t(128), N=p(32), K=s(128) ----
  f32x4 acc[2][2] = {};
  #pragma unroll
  for (int ks = 0; ks < 4; ++ks){
    int kb = ks*64 + l4*16;
    int t0 = wid*32 + l15, t1 = t0+16;
    short8 a0 = *(const short8*)(sAttn + ((t0*256 + kb) ^ ((t0&7)<<4)));
    short8 a1 = *(const short8*)(sAttn + ((t1*256 + kb) ^ ((t1&7)<<4)));
    short8 b0 = *(const short8*)(sXT + ((l15*256 + kb) ^ ((l15&7)<<4)));
    short8 b1 = *(const short8*)(sXT + (((16+l15)*256 + kb) ^ (((16+l15)&7)<<4)));
    acc[0][0] = MFMA16(a0,b0,acc[0][0]);
    acc[0][1] = MFMA16(a0,b1,acc[0][1]);
    acc[1][0] = MFMA16(a1,b0,acc[1][0]);
    acc[1][1] = MFMA16(a1,b1,acc[1][1]);
  }
  #pragma unroll
  for (int mt=0; mt<2; ++mt)
  #pragma unroll
  for (int nt=0; nt<2; ++nt)
  #pragma unroll
  for (int r=0; r<4; ++r){
    int t = wid*32 + mt*16 + l4*4 + r;
    int p = nt*16 + l15;
    Y[(rb+t)*512 + h*32 + p] = acc[mt][nt][r];
  }
  // ---- states = xw @ B : M=p(32), N=n(256), K=s(128) ----
  f32x4 acc2[2][4] = {};
  #pragma unroll
  for (int ks = 0; ks < 4; ++ks){
    int kb = ks*64 + l4*16;
    short8 a0 = *(const short8*)(sXW + ((l15*256 + kb) ^ ((l15&7)<<4)));
    short8 a1 = *(const short8*)(sXW + (((16+l15)*256 + kb) ^ (((16+l15)&7)<<4)));
    #pragma unroll
    for (int ntl = 0; ntl < 4; ++ntl){
      int n = wid*64 + ntl*16 + l15;
      short8 b = *(const short8*)(bt + (size_t)n*128 + ks*32 + l4*8);
      acc2[0][ntl] = MFMA16(a0,b,acc2[0][ntl]);
      acc2[1][ntl] = MFMA16(a1,b,acc2[1][ntl]);
    }
  }
  #pragma unroll
  for (int mt=0; mt<2; ++mt)
  #pragma unroll
  for (int ntl=0; ntl<4; ++ntl)
  #pragma unroll
  for (int r=0; r<4; ++r){
    int p = mt*16 + l4*4 + r;
    int n = wid*64 + ntl*16 + l15;
    st[p*256 + n] = f2bf(acc2[mt][ntl][r]);
  }
}

// ---------------- K5: sequential chunk scan (bf16 in place) ---------------------
__global__ __launch_bounds__(256) void k5_scan(char* __restrict__ wsb){
  int g = blockIdx.x*256 + threadIdx.x;   // 262144 threads
  int n = g & 255; int p = (g>>8)&31; int h = (g>>13)&15; int b = g>>17;
  ushort* st = (ushort*)(wsb + OFF_ST);
  const float* cdc = (const float*)(wsb + OFF_CDC);
  float S = 0.f;
  for (int c=0; c<64; ++c){
    int bi = (b*64+c)*16 + h;
    size_t idx = (size_t)bi*8192 + (size_t)p*256 + n;
    float v = bf2f(st[idx]);
    st[idx] = f2bf(S);
    S = fmaf(S, cdc[bi], v);
  }
}

// ---------------- K6: y += exp(cum[t]) * C@prev^T + D*xs  (MFMA, LDS-free) ------
__global__ __launch_bounds__(256) void k6_yinter(const float* __restrict__ Dp,
                                                 char* __restrict__ wsb){
  int bi = blockIdx.x;                    // (b*64+c)*16 + h
  int h = bi & 15; int bc = bi >> 4;
  __shared__ float sE[128];
  const ushort* bcm  = (const ushort*)(wsb + OFF_BCM);
  const ushort* prev = (const ushort*)(wsb + OFF_ST) + (size_t)bi*8192;
  const ushort* xs   = (const ushort*)(wsb + OFF_XS);
  const float* cum   = (const float*)(wsb + OFF_CUM) + (size_t)bi*128;
  float* Y = (float*)(wsb + OFF_Y);
  size_t rb = (size_t)bc*128;
  int tid = threadIdx.x;
  if (tid < 128) sE[tid] = __expf(cum[tid]);
  __syncthreads();
  int lane = tid&63, wid = tid>>6, l15 = lane&15, l4 = lane>>4;
  f32x4 acc[2][2] = {};
  #pragma unroll
  for (int ks = 0; ks < 8; ++ks){
    int koff = ks*32 + l4*8;
    int t0 = wid*32 + l15;
    short8 a0 = *(const short8*)(bcm + (rb+t0)*512 + 256 + koff);
    short8 a1 = *(const short8*)(bcm + (rb+t0+16)*512 + 256 + koff);
    short8 b0 = *(const short8*)(prev + (size_t)l15*256 + koff);
    short8 b1 = *(const short8*)(prev + (size_t)(16+l15)*256 + koff);
    acc[0][0] = MFMA16(a0,b0,acc[0][0]);
    acc[0][1] = MFMA16(a0,b1,acc[0][1]);
    acc[1][0] = MFMA16(a1,b0,acc[1][0]);
    acc[1][1] = MFMA16(a1,b1,acc[1][1]);
  }
  float Dh = Dp[h];
  #pragma unroll
  for (int mt=0; mt<2; ++mt)
  #pragma unroll
  for (int nt=0; nt<2; ++nt)
  #pragma unroll
  for (int r=0; r<4; ++r){
    int t = wid*32 + mt*16 + l4*4 + r;
    int p = nt*16 + l15;
    size_t a = (rb+t)*512 + h*32 + p;
    Y[a] = Y[a] + sE[t]*acc[mt][nt][r] + Dh*bf2f(xs[a]);
  }
}

// ---------------- K7: gate(silu(z)) -> RMS -> out_proj (MFMA) -------------------
__global__ __launch_bounds__(256) void k7_final(const float* __restrict__ x,
                                                char* __restrict__ wsb,
                                                float* __restrict__ out){
  int r0 = blockIdx.x*32;                  // 512 blocks
  __shared__ __align__(16) char sG[32768]; // G[32][512] bf16 rows 1024B, swizzled
  __shared__ float sScale[32];
  const float* Y  = (const float*)(wsb + OFF_Y);
  const float* M  = (const float*)(wsb + OFF_M);
  const float* Cb = (const float*)(wsb + OFF_CB_B);
  const ushort* WT = (const ushort*)(wsb + OFF_WT);
  int tid = threadIdx.x;
  int r = tid>>3, li = tid&7;
  int row = r0 + r; int b = row>>13, l = row & 8191;
  int hh, wv;
  if (l < 4096){ hh = l>>6; wv = l&63; }
  else { int l2 = l-4096; hh = 63-(l2>>6); wv = 63-(l2&63); }
  const float* xb = x + (size_t)b*12288;
  float x0 = xb[hh*64+wv], x1 = xb[4096+hh*64+wv], x2 = xb[8192+hh*64+wv];
  float sq = 0.f;
  for (int k = 0; k < 64; ++k){
    int i = li + 8*k;
    float z = Cb[i];
    z = fmaf(x0, M[i], z);
    z = fmaf(x1, M[DPROJ+i], z);
    z = fmaf(x2, M[2*DPROJ+i], z);
    float y = Y[(size_t)row*512 + i];
    float g = y * z * sigm(z);
    sq = fmaf(g, g, sq);
    *(ushort*)(sG + ((r*1024 + i*2) ^ ((r&7)<<4))) = f2bf(g);
  }
  sq += __shfl_xor(sq, 1, 64);
  sq += __shfl_xor(sq, 2, 64);
  sq += __shfl_xor(sq, 4, 64);
  if (li == 0) sScale[r] = rsqrtf(sq*(1.f/512.f) + 1e-5f);
  __syncthreads();
  int lane = tid&63, wid = tid>>6, l15 = lane&15, l4 = lane>>4;
  f32x4 acc[2][2] = {};
  #pragma unroll
  for (int ks = 0; ks < 16; ++ks){
    int kb = ks*64 + l4*16;
    int rr0 = l15, rr1 = 16+l15;
    short8 a0 = *(const short8*)(sG + ((rr0*1024 + kb) ^ ((rr0&7)<<4)));
    short8 a1 = *(const short8*)(sG + ((rr1*1024 + kb) ^ ((rr1&7)<<4)));
    int koff = ks*32 + l4*8;
    short8 b0 = *(const short8*)(WT + (size_t)(wid*32 + l15)*512 + koff);
    short8 b1 = *(const short8*)(WT + (size_t)(wid*32 + 16 + l15)*512 + koff);
    acc[0][0] = MFMA16(a0,b0,acc[0][0]);
    acc[0][1] = MFMA16(a0,b1,acc[0][1]);
    acc[1][0] = MFMA16(a1,b0,acc[1][0]);
    acc[1][1] = MFMA16(a1,b1,acc[1][1]);
  }
  #pragma unroll
  for (int mt=0; mt<2; ++mt)
  #pragma unroll
  for (int nt=0; nt<2; ++nt)
  #pragma unroll
  for (int r4=0; r4<4; ++r4){
    int rr = mt*16 + l4*4 + r4;
    int d = wid*32 + nt*16 + l15;
    out[(size_t)(r0+rr)*128 + d] = acc[mt][nt][r4] * sScale[rr];
  }
}

extern "C" void kernel_launch(void* const* d_in, const int* in_sizes, int n_in,
                              void* d_out, int out_size, void* d_ws, size_t ws_size,
                              hipStream_t stream) {
  const float* x         = (const float*)d_in[0];
  const float* fc0_w     = (const float*)d_in[1];
  const float* fc0_b     = (const float*)d_in[2];
  const float* in_proj_w = (const float*)d_in[3];
  const float* conv_w    = (const float*)d_in[4];
  const float* conv_b    = (const float*)d_in[5];
  const float* dt_bias   = (const float*)d_in[6];
  const float* A_log     = (const float*)d_in[7];
  const float* Dp        = (const float*)d_in[8];
  const float* norm_w    = (const float*)d_in[9];
  const float* out_proj_w= (const float*)d_in[10];
  char* wsb  = (char*)d_ws;
  float* out = (float*)d_out;

  k0_prep<<<dim3(7),     dim3(256), 0, stream>>>(fc0_w, fc0_b, in_proj_w, wsb);
  k0b_wt <<<dim3(128),   dim3(256), 0, stream>>>(norm_w, out_proj_w, wsb);
  k1dt   <<<dim3(1024),  dim3(256), 0, stream>>>(x, dt_bias, wsb);
  k12_projconv<<<dim3(1024), dim3(256), 0, stream>>>(x, conv_w, conv_b, wsb);
  k3_cum <<<dim3(2048),  dim3(128), 0, stream>>>(A_log, wsb);
  k4a_cb <<<dim3(512),   dim3(256), 0, stream>>>(wsb);
  k4t_bt <<<dim3(128),   dim3(256), 0, stream>>>(wsb);
  k4b_intra_states<<<dim3(2048), dim3(256), 0, stream>>>(wsb);
  k5_scan<<<dim3(1024),  dim3(256), 0, stream>>>(wsb);
  k6_yinter<<<dim3(2048), dim3(256), 0, stream>>>(Dp, wsb);
  k7_final<<<dim3(512),  dim3(256), 0, stream>>>(x, wsb, out);
}

// Round 4
// 190.153 us; speedup vs baseline: 3.1250x; 1.0683x over previous
//
#include <hip/hip_runtime.h>

typedef short short8 __attribute__((ext_vector_type(8)));
typedef float f32x4 __attribute__((ext_vector_type(4)));
typedef unsigned short ushort;
typedef unsigned int uint;

#define MFMA16(a,b,c) __builtin_amdgcn_mfma_f32_16x16x32_bf16(a,b,c,0,0,0)
#define DPROJ 1552

// ---- workspace byte offsets ----
constexpr size_t OFF_M    = 0;                         // 3*1552 f32
constexpr size_t OFF_CB_B = 0x5000;                    // 1552 f32
constexpr size_t OFF_WT   = 0x8000;                    // 128*512 bf16 (WoutT * norm_w)
constexpr size_t OFF_XPRE = 0x30000;                   // (unused)
constexpr size_t OFF_DT   = OFF_XPRE + 33554432ull;    // 16384*16 f32
constexpr size_t OFF_XS   = OFF_DT   + 1048576ull;     // 16384*512 bf16
constexpr size_t OFF_BCM  = OFF_XS   + 16777216ull;    // 16384*512 bf16  [B(256)|C(256)]
constexpr size_t OFF_CUM  = OFF_BCM  + 16777216ull;    // 2048*128 f32
constexpr size_t OFF_CDC  = OFF_CUM  + 1048576ull;     // 2048 f32
constexpr size_t OFF_CBT  = OFF_CDC  + 8192ull;        // 128*(128*128) bf16 [t][s]
constexpr size_t OFF_BT   = OFF_CBT  + 4194304ull;     // 128*(256*128) bf16 [n][s]
constexpr size_t OFF_ST   = OFF_BT   + 8388608ull;     // 2048*(32*256) bf16 [p][n]
constexpr size_t OFF_Y    = OFF_ST   + 33554432ull;    // 16384*512 f32

__device__ __forceinline__ float sigm(float x){ return 1.0f/(1.0f + __expf(-x)); }
__device__ __forceinline__ ushort f2bf(float f){
  union { float f; uint u; } c; c.f = f;
  uint u = c.u;
  return (ushort)((u + 0x7FFFu + ((u>>16)&1u)) >> 16);
}
__device__ __forceinline__ float bf2f(ushort h){
  union { uint u; float f; } c; c.u = ((uint)h)<<16;
  return c.f;
}
// XCD swizzle for 2048-block grids: all 16 heads of one (b,c) on one XCD
__device__ __forceinline__ void swz2048(int p, int& bc, int& h){
  int xcd = p & 7, slot = p >> 3;
  bc = xcd*16 + (slot >> 4);
  h  = slot & 15;
}

// ---------------- K0: fuse fc0 into in_proj ----------------
__global__ __launch_bounds__(256) void k0_prep(const float* __restrict__ fc0_w,
                                               const float* __restrict__ fc0_b,
                                               const float* __restrict__ W,
                                               char* __restrict__ wsb){
  float* Mo = (float*)(wsb + OFF_M);
  float* Co = (float*)(wsb + OFF_CB_B);
  int j = blockIdx.x*256 + threadIdx.x;
  if (j >= DPROJ) return;
  float m0=0.f,m1=0.f,m2=0.f,cc=0.f;
  for (int d=0; d<128; ++d){
    float w = W[(size_t)d*DPROJ + j];
    m0 = fmaf(fc0_w[d],     w, m0);
    m1 = fmaf(fc0_w[128+d], w, m1);
    m2 = fmaf(fc0_w[256+d], w, m2);
    cc = fmaf(fc0_b[d],     w, cc);
  }
  Mo[j] = m0; Mo[DPROJ + j] = m1; Mo[2*DPROJ + j] = m2;
  Co[j] = cc;
}

// ---------------- K0b: WoutT'[d][i] = norm_w[i]*Wout[i][d]  (bf16) --------------
__global__ __launch_bounds__(256) void k0b_wt(const float* __restrict__ norm_w,
                                              const float* __restrict__ Wout,
                                              char* __restrict__ wsb){
  ushort* WT = (ushort*)(wsb + OFF_WT);
  int d = blockIdx.x;
  for (int i = threadIdx.x; i < 512; i += 256)
    WT[(size_t)d*512 + i] = f2bf(norm_w[i]*Wout[(size_t)i*128 + d]);
}

// ---------------- K1dt: dt = softplus(proj + bias) ------------------------------
__global__ __launch_bounds__(256) void k1dt(const float* __restrict__ x,
                                            const float* __restrict__ dt_bias,
                                            char* __restrict__ wsb){
  int idx = blockIdx.x*256 + threadIdx.x;   // 262144
  int r = idx >> 4, hh = idx & 15;
  int b = r >> 13, l = r & 8191;
  int hp, wv;
  if (l < 4096){ hp = l>>6; wv = l&63; }
  else { int l2 = l-4096; hp = 63-(l2>>6); wv = 63-(l2&63); }
  const float* xb = x + (size_t)b*12288;
  float x0 = xb[hp*64+wv], x1 = xb[4096+hp*64+wv], x2 = xb[8192+hp*64+wv];
  const float* M  = (const float*)(wsb + OFF_M);
  const float* Cc = (const float*)(wsb + OFF_CB_B);
  int j = 1536 + hh;
  float v = Cc[j];
  v = fmaf(x0, M[j], v);
  v = fmaf(x1, M[DPROJ+j], v);
  v = fmaf(x2, M[2*DPROJ+j], v);
  float t = v + dt_bias[hh];
  ((float*)(wsb+OFF_DT))[(size_t)r*16+hh] = (t > 20.f) ? t : log1pf(__expf(t));
}

// ------ K12: fused proj+causal conv(4)+silu -> xs / BC --------------------------
__device__ __forceinline__ void proj8(int li, const float* __restrict__ xb,
                                      const float* m0, const float* m1, const float* m2,
                                      const float* c8, float* dst){
  if (li < 0){
    #pragma unroll
    for (int j=0;j<8;++j) dst[j] = 0.f;
    return;
  }
  int hh, wv;
  if (li < 4096){ hh = li>>6; wv = li&63; }
  else { int l2 = li-4096; hh = 63-(l2>>6); wv = 63-(l2&63); }
  float x0 = xb[hh*64+wv], x1 = xb[4096+hh*64+wv], x2 = xb[8192+hh*64+wv];
  #pragma unroll
  for (int j=0;j<8;++j)
    dst[j] = fmaf(x2, m2[j], fmaf(x1, m1[j], fmaf(x0, m0[j], c8[j])));
}

__device__ __forceinline__ void emit8(ushort* __restrict__ outp, size_t row,
                                      const float* cb8, const float* cw0, const float* cw1,
                                      const float* cw2, const float* cw3,
                                      const float* wA, const float* wB,
                                      const float* wC, const float* wD){
  ushort o[8];
  #pragma unroll
  for (int j=0;j<8;++j){
    float a = cb8[j];
    a = fmaf(wA[j], cw0[j], a);
    a = fmaf(wB[j], cw1[j], a);
    a = fmaf(wC[j], cw2[j], a);
    a = fmaf(wD[j], cw3[j], a);
    o[j] = f2bf(a * sigm(a));
  }
  *(uint4*)(outp + row*512) = *(uint4*)o;
}

__global__ __launch_bounds__(256) void k12_projconv(const float* __restrict__ x,
                                                    const float* __restrict__ conv_w,
                                                    const float* __restrict__ conv_b,
                                                    char* __restrict__ wsb){
  int tid = threadIdx.x;
  int cg = tid & 127, rl = tid >> 7;
  int row0 = blockIdx.x*16 + rl*8;        // 1024 blocks, 16 rows each
  int b = row0 >> 13, l0 = row0 & 8191;
  const float* M  = (const float*)(wsb + OFF_M);
  const float* Cc = (const float*)(wsb + OFF_CB_B);
  const float* xb = x + (size_t)b*12288;
  int ch0 = cg*8, j0 = 512 + ch0;
  float m0[8],m1[8],m2[8],c8[8],cw0[8],cw1[8],cw2[8],cw3[8],cb8[8];
  #pragma unroll
  for (int j=0;j<8;++j){
    m0[j]=M[j0+j]; m1[j]=M[DPROJ+j0+j]; m2[j]=M[2*DPROJ+j0+j]; c8[j]=Cc[j0+j];
    cw0[j]=conv_w[(ch0+j)*4+0]; cw1[j]=conv_w[(ch0+j)*4+1];
    cw2[j]=conv_w[(ch0+j)*4+2]; cw3[j]=conv_w[(ch0+j)*4+3];
    cb8[j]=conv_b[ch0+j];
  }
  ushort* outp = (ch0 < 512) ? ((ushort*)(wsb+OFF_XS) + ch0)
                             : ((ushort*)(wsb+OFF_BCM) + (ch0-512));
  float w0[8],w1[8],w2[8],w3[8];
  proj8(l0-3, xb, m0,m1,m2,c8, w1);
  proj8(l0-2, xb, m0,m1,m2,c8, w2);
  proj8(l0-1, xb, m0,m1,m2,c8, w3);
  #pragma unroll
  for (int it=0; it<2; ++it){
    int l = l0 + it*4;
    size_t r = (size_t)row0 + it*4;
    proj8(l,   xb, m0,m1,m2,c8, w0); emit8(outp, r,   cb8,cw0,cw1,cw2,cw3, w1,w2,w3,w0);
    proj8(l+1, xb, m0,m1,m2,c8, w1); emit8(outp, r+1, cb8,cw0,cw1,cw2,cw3, w2,w3,w0,w1);
    proj8(l+2, xb, m0,m1,m2,c8, w2); emit8(outp, r+2, cb8,cw0,cw1,cw2,cw3, w3,w0,w1,w2);
    proj8(l+3, xb, m0,m1,m2,c8, w3); emit8(outp, r+3, cb8,cw0,cw1,cw2,cw3, w0,w1,w2,w3);
  }
}

// ---------------- K3: per (b,c,h) inclusive cumsum of dt*A ----------------------
__global__ __launch_bounds__(128) void k3_cum(const float* __restrict__ A_log,
                                              char* __restrict__ wsb){
  int bi = blockIdx.x;                    // (b*64+c)*16 + h
  int h = bi & 15;
  int t = threadIdx.x;
  __shared__ float s[128];
  float A = -__expf(A_log[h]);
  const float* dtp = (const float*)(wsb + OFF_DT);
  size_t row = (size_t)(bi>>4)*128 + t;
  float a = dtp[row*16 + h] * A;
  s[t] = a; __syncthreads();
  for (int off=1; off<128; off<<=1){
    float v = (t>=off) ? s[t-off] : 0.f;
    __syncthreads();
    s[t] += v;
    __syncthreads();
  }
  ((float*)(wsb + OFF_CUM))[(size_t)bi*128 + t] = s[t];
  if (t==127) ((float*)(wsb + OFF_CDC))[bi] = __expf(s[127]);
}

// ---------------- K4a: CB[t][s] = sum_n C[t,n]B[s,n]  via MFMA ------------------
__global__ __launch_bounds__(256) void k4a_cb(char* __restrict__ wsb){
  int bi = blockIdx.x;                    // (b*64+c)*4 + squad
  int sq = bi & 3; int bc = bi >> 2;
  __shared__ __align__(16) char sC[16384];   // C[128][64] bf16 swizzled rows(128B)
  __shared__ __align__(16) char sB[4096];    // B[32][64]  bf16 swizzled
  const ushort* bcm = (const ushort*)(wsb + OFF_BCM);
  ushort* cbt = (ushort*)(wsb + OFF_CBT) + (size_t)bc*16384;
  size_t rb = (size_t)bc*128;
  int tid = threadIdx.x;
  int lane = tid&63, wid = tid>>6, l15 = lane&15, l4 = lane>>4;
  int s_base = sq*32;
  f32x4 acc[2][2] = {};
  for (int nt = 0; nt < 4; ++nt){
    int n0 = nt*64;
    __syncthreads();
    for (int idx = tid; idx < 1024; idx += 256){
      int t = idx>>3, c = idx&7;
      uint4 v = *(const uint4*)(bcm + (rb+t)*512 + 256 + n0 + c*8);
      *(uint4*)(sC + ((t*128 + c*16) ^ ((t&7)<<4))) = v;
    }
    {
      int idx = tid;  // exactly 256 chunks
      int s = idx>>3, c = idx&7;
      uint4 v = *(const uint4*)(bcm + (rb+s_base+s)*512 + n0 + c*8);
      *(uint4*)(sB + ((s*128 + c*16) ^ ((s&7)<<4))) = v;
    }
    __syncthreads();
    #pragma unroll
    for (int ks = 0; ks < 2; ++ks){
      int kb = ks*64 + l4*16;
      int t0 = wid*32 + l15, t1 = t0 + 16;
      short8 a0 = *(const short8*)(sC + ((t0*128 + kb) ^ ((t0&7)<<4)));
      short8 a1 = *(const short8*)(sC + ((t1*128 + kb) ^ ((t1&7)<<4)));
      short8 b0 = *(const short8*)(sB + ((l15*128 + kb) ^ ((l15&7)<<4)));
      short8 b1 = *(const short8*)(sB + (((16+l15)*128 + kb) ^ (((16+l15)&7)<<4)));
      acc[0][0] = MFMA16(a0,b0,acc[0][0]);
      acc[0][1] = MFMA16(a0,b1,acc[0][1]);
      acc[1][0] = MFMA16(a1,b0,acc[1][0]);
      acc[1][1] = MFMA16(a1,b1,acc[1][1]);
    }
  }
  #pragma unroll
  for (int mt=0; mt<2; ++mt)
  #pragma unroll
  for (int st=0; st<2; ++st)
  #pragma unroll
  for (int r=0; r<4; ++r){
    int t = wid*32 + mt*16 + l4*4 + r;
    int s = s_base + st*16 + l15;
    cbt[t*128 + s] = f2bf(acc[mt][st][r]);
  }
}

// ---------------- K4t: Bt[n][s] transpose (per b,c) -----------------------------
__global__ __launch_bounds__(256) void k4t_bt(char* __restrict__ wsb){
  int bc = blockIdx.x; int n = threadIdx.x;
  const ushort* bcm = (const ushort*)(wsb + OFF_BCM);
  size_t rb = (size_t)bc*128;
  uint pk[64];
  #pragma unroll
  for (int s2 = 0; s2 < 64; ++s2){
    uint lo = bcm[(rb + 2*s2  )*512 + n];
    uint hi = bcm[(rb + 2*s2+1)*512 + n];
    pk[s2] = lo | (hi<<16);
  }
  uint4* out = (uint4*)((ushort*)(wsb + OFF_BT) + (size_t)bc*32768 + (size_t)n*128);
  #pragma unroll
  for (int k=0;k<16;++k){
    uint4 v; v.x = pk[4*k]; v.y = pk[4*k+1]; v.z = pk[4*k+2]; v.w = pk[4*k+3];
    out[k] = v;
  }
}

// -------- K4s: per (b,c,h): states = (x*w)^T @ B  (pre-scan) --------------------
__global__ __launch_bounds__(256) void k4s_states(char* __restrict__ wsb){
  int bc, h; swz2048(blockIdx.x, bc, h);
  int bi = bc*16 + h;
  __shared__ __align__(16) char sXW[8192];     // [p][s]*w[s] bf16, swizzled rows 256B
  __shared__ float sW[128];
  const ushort* xs  = (const ushort*)(wsb + OFF_XS);
  const ushort* bt  = (const ushort*)(wsb + OFF_BT) + (size_t)bc*32768;
  const float* cum  = (const float*)(wsb + OFF_CUM) + (size_t)bi*128;
  const float* dtp  = (const float*)(wsb + OFF_DT);
  ushort* st = (ushort*)(wsb + OFF_ST) + (size_t)bi*8192;
  size_t rb = (size_t)bc*128;
  int tid = threadIdx.x;
  if (tid < 128){
    float c127 = cum[127];
    sW[tid] = __expf(c127 - cum[tid]) * dtp[(rb+tid)*16 + h];
  }
  __syncthreads();
  for (int idx = tid; idx < 4096; idx += 256){
    int s = idx>>5, p = idx&31;
    float v = bf2f(xs[(rb+s)*512 + h*32 + p]) * sW[s];
    *(ushort*)(sXW + ((p*256 + s*2) ^ ((p&7)<<4))) = f2bf(v);
  }
  __syncthreads();
  int lane = tid&63, wid = tid>>6, l15 = lane&15, l4 = lane>>4;
  f32x4 acc2[2][4] = {};
  #pragma unroll
  for (int ks = 0; ks < 4; ++ks){
    int kb = ks*64 + l4*16;
    short8 a0 = *(const short8*)(sXW + ((l15*256 + kb) ^ ((l15&7)<<4)));
    short8 a1 = *(const short8*)(sXW + (((16+l15)*256 + kb) ^ (((16+l15)&7)<<4)));
    #pragma unroll
    for (int ntl = 0; ntl < 4; ++ntl){
      int n = wid*64 + ntl*16 + l15;
      short8 b = *(const short8*)(bt + (size_t)n*128 + ks*32 + l4*8);
      acc2[0][ntl] = MFMA16(a0,b,acc2[0][ntl]);
      acc2[1][ntl] = MFMA16(a1,b,acc2[1][ntl]);
    }
  }
  #pragma unroll
  for (int mt=0; mt<2; ++mt)
  #pragma unroll
  for (int ntl=0; ntl<4; ++ntl)
  #pragma unroll
  for (int r=0; r<4; ++r){
    int p = mt*16 + l4*4 + r;
    int n = wid*64 + ntl*16 + l15;
    st[p*256 + n] = f2bf(acc2[mt][ntl][r]);
  }
}

// ---------------- K5: sequential chunk scan (bf16 in place) ---------------------
__global__ __launch_bounds__(256) void k5_scan(char* __restrict__ wsb){
  int g = blockIdx.x*256 + threadIdx.x;   // 262144 threads
  int n = g & 255; int p = (g>>8)&31; int h = (g>>13)&15; int b = g>>17;
  ushort* st = (ushort*)(wsb + OFF_ST);
  const float* cdc = (const float*)(wsb + OFF_CDC);
  float S = 0.f;
  for (int c=0; c<64; ++c){
    int bi = (b*64+c)*16 + h;
    size_t idx = (size_t)bi*8192 + (size_t)p*256 + n;
    float v = bf2f(st[idx]);
    st[idx] = f2bf(S);
    S = fmaf(S, cdc[bi], v);
  }
}

// -------- K4y: per (b,c,h): y = attn@x + exp(cum)*C@prev + D*x  (post-scan) -----
__global__ __launch_bounds__(256) void k4y_out(const float* __restrict__ Dp,
                                               char* __restrict__ wsb){
  int bc, h; swz2048(blockIdx.x, bc, h);
  int bi = bc*16 + h;
  __shared__ __align__(16) char sAttn[32768];  // [t][s] bf16, rows 256B, swizzled
  __shared__ __align__(16) char sXT[8192];     // [p][s] bf16
  __shared__ float sCum[128], sDt[128], sE[128];
  const ushort* cbt = (const ushort*)(wsb + OFF_CBT) + (size_t)bc*16384;
  const ushort* xs  = (const ushort*)(wsb + OFF_XS);
  const ushort* bcm = (const ushort*)(wsb + OFF_BCM);
  const ushort* prev= (const ushort*)(wsb + OFF_ST) + (size_t)bi*8192;
  const float* cum  = (const float*)(wsb + OFF_CUM) + (size_t)bi*128;
  const float* dtp  = (const float*)(wsb + OFF_DT);
  float* Y = (float*)(wsb + OFF_Y);
  size_t rb = (size_t)bc*128;
  int tid = threadIdx.x;
  // stage CB
  for (int idx = tid; idx < 2048; idx += 256){
    int t = idx>>4, c = idx&15;
    uint4 v = *(const uint4*)(cbt + t*128 + c*8);
    *(uint4*)(sAttn + ((t*256 + c*16) ^ ((t&7)<<4))) = v;
  }
  // stage x transposed
  for (int idx = tid; idx < 4096; idx += 256){
    int s = idx>>5, p = idx&31;
    ushort v = xs[(rb+s)*512 + h*32 + p];
    *(ushort*)(sXT + ((p*256 + s*2) ^ ((p&7)<<4))) = v;
  }
  if (tid < 128){ sCum[tid] = cum[tid]; sDt[tid] = dtp[(rb+tid)*16 + h]; }
  __syncthreads();
  if (tid < 128) sE[tid] = __expf(sCum[tid]);
  // attn in-place transform
  for (int idx = tid; idx < 16384; idx += 256){
    int t = idx>>7, s = idx&127;
    ushort* a = (ushort*)(sAttn + ((t*256 + s*2) ^ ((t&7)<<4)));
    float v = 0.f;
    if (t >= s) v = bf2f(*a) * __expf(sCum[t]-sCum[s]) * sDt[s];
    *a = f2bf(v);
  }
  __syncthreads();
  int lane = tid&63, wid = tid>>6, l15 = lane&15, l4 = lane>>4;
  // ---- y_intra = attn @ x : M=t(128), N=p(32), K=s(128) ----
  f32x4 acc[2][2] = {};
  #pragma unroll
  for (int ks = 0; ks < 4; ++ks){
    int kb = ks*64 + l4*16;
    int t0 = wid*32 + l15, t1 = t0+16;
    short8 a0 = *(const short8*)(sAttn + ((t0*256 + kb) ^ ((t0&7)<<4)));
    short8 a1 = *(const short8*)(sAttn + ((t1*256 + kb) ^ ((t1&7)<<4)));
    short8 b0 = *(const short8*)(sXT + ((l15*256 + kb) ^ ((l15&7)<<4)));
    short8 b1 = *(const short8*)(sXT + (((16+l15)*256 + kb) ^ (((16+l15)&7)<<4)));
    acc[0][0] = MFMA16(a0,b0,acc[0][0]);
    acc[0][1] = MFMA16(a0,b1,acc[0][1]);
    acc[1][0] = MFMA16(a1,b0,acc[1][0]);
    acc[1][1] = MFMA16(a1,b1,acc[1][1]);
  }
  // ---- y_inter = C @ prev^T : M=t(128), N=p(32), K=n(256), direct from global --
  f32x4 acc2[2][2] = {};
  #pragma unroll
  for (int ks = 0; ks < 8; ++ks){
    int koff = ks*32 + l4*8;
    int t0 = wid*32 + l15;
    short8 a0 = *(const short8*)(bcm + (rb+t0)*512 + 256 + koff);
    short8 a1 = *(const short8*)(bcm + (rb+t0+16)*512 + 256 + koff);
    short8 b0 = *(const short8*)(prev + (size_t)l15*256 + koff);
    short8 b1 = *(const short8*)(prev + (size_t)(16+l15)*256 + koff);
    acc2[0][0] = MFMA16(a0,b0,acc2[0][0]);
    acc2[0][1] = MFMA16(a0,b1,acc2[0][1]);
    acc2[1][0] = MFMA16(a1,b0,acc2[1][0]);
    acc2[1][1] = MFMA16(a1,b1,acc2[1][1]);
  }
  float Dh = Dp[h];
  #pragma unroll
  for (int mt=0; mt<2; ++mt)
  #pragma unroll
  for (int nt=0; nt<2; ++nt)
  #pragma unroll
  for (int r=0; r<4; ++r){
    int t = wid*32 + mt*16 + l4*4 + r;
    int p = nt*16 + l15;
    size_t a = (rb+t)*512 + h*32 + p;
    Y[a] = acc[mt][nt][r] + sE[t]*acc2[mt][nt][r] + Dh*bf2f(xs[a]);
  }
}

// ---------------- K7: gate(silu(z)) -> RMS -> out_proj (MFMA) -------------------
__global__ __launch_bounds__(256) void k7_final(const float* __restrict__ x,
                                                char* __restrict__ wsb,
                                                float* __restrict__ out){
  int r0 = blockIdx.x*32;                  // 512 blocks
  __shared__ __align__(16) char sG[32768]; // G[32][512] bf16 rows 1024B, swizzled
  __shared__ float sScale[32];
  const float* Y  = (const float*)(wsb + OFF_Y);
  const float* M  = (const float*)(wsb + OFF_M);
  const float* Cb = (const float*)(wsb + OFF_CB_B);
  const ushort* WT = (const ushort*)(wsb + OFF_WT);
  int tid = threadIdx.x;
  int r = tid>>3, li = tid&7;
  int row = r0 + r; int b = row>>13, l = row & 8191;
  int hh, wv;
  if (l < 4096){ hh = l>>6; wv = l&63; }
  else { int l2 = l-4096; hh = 63-(l2>>6); wv = 63-(l2&63); }
  const float* xb = x + (size_t)b*12288;
  float x0 = xb[hh*64+wv], x1 = xb[4096+hh*64+wv], x2 = xb[8192+hh*64+wv];
  float sq = 0.f;
  for (int k = 0; k < 64; ++k){
    int i = li + 8*k;
    float z = Cb[i];
    z = fmaf(x0, M[i], z);
    z = fmaf(x1, M[DPROJ+i], z);
    z = fmaf(x2, M[2*DPROJ+i], z);
    float y = Y[(size_t)row*512 + i];
    float g = y * z * sigm(z);
    sq = fmaf(g, g, sq);
    *(ushort*)(sG + ((r*1024 + i*2) ^ ((r&7)<<4))) = f2bf(g);
  }
  sq += __shfl_xor(sq, 1, 64);
  sq += __shfl_xor(sq, 2, 64);
  sq += __shfl_xor(sq, 4, 64);
  if (li == 0) sScale[r] = rsqrtf(sq*(1.f/512.f) + 1e-5f);
  __syncthreads();
  int lane = tid&63, wid = tid>>6, l15 = lane&15, l4 = lane>>4;
  f32x4 acc[2][2] = {};
  #pragma unroll
  for (int ks = 0; ks < 16; ++ks){
    int kb = ks*64 + l4*16;
    int rr0 = l15, rr1 = 16+l15;
    short8 a0 = *(const short8*)(sG + ((rr0*1024 + kb) ^ ((rr0&7)<<4)));
    short8 a1 = *(const short8*)(sG + ((rr1*1024 + kb) ^ ((rr1&7)<<4)));
    int koff = ks*32 + l4*8;
    short8 b0 = *(const short8*)(WT + (size_t)(wid*32 + l15)*512 + koff);
    short8 b1 = *(const short8*)(WT + (size_t)(wid*32 + 16 + l15)*512 + koff);
    acc[0][0] = MFMA16(a0,b0,acc[0][0]);
    acc[0][1] = MFMA16(a0,b1,acc[0][1]);
    acc[1][0] = MFMA16(a1,b0,acc[1][0]);
    acc[1][1] = MFMA16(a1,b1,acc[1][1]);
  }
  #pragma unroll
  for (int mt=0; mt<2; ++mt)
  #pragma unroll
  for (int nt=0; nt<2; ++nt)
  #pragma unroll
  for (int r4=0; r4<4; ++r4){
    int rr = mt*16 + l4*4 + r4;
    int d = wid*32 + nt*16 + l15;
    out[(size_t)(r0+rr)*128 + d] = acc[mt][nt][r4] * sScale[rr];
  }
}

extern "C" void kernel_launch(void* const* d_in, const int* in_sizes, int n_in,
                              void* d_out, int out_size, void* d_ws, size_t ws_size,
                              hipStream_t stream) {
  const float* x         = (const float*)d_in[0];
  const float* fc0_w     = (const float*)d_in[1];
  const float* fc0_b     = (const float*)d_in[2];
  const float* in_proj_w = (const float*)d_in[3];
  const float* conv_w    = (const float*)d_in[4];
  const float* conv_b    = (const float*)d_in[5];
  const float* dt_bias   = (const float*)d_in[6];
  const float* A_log     = (const float*)d_in[7];
  const float* Dp        = (const float*)d_in[8];
  const float* norm_w    = (const float*)d_in[9];
  const float* out_proj_w= (const float*)d_in[10];
  char* wsb  = (char*)d_ws;
  float* out = (float*)d_out;

  k0_prep<<<dim3(7),     dim3(256), 0, stream>>>(fc0_w, fc0_b, in_proj_w, wsb);
  k0b_wt <<<dim3(128),   dim3(256), 0, stream>>>(norm_w, out_proj_w, wsb);
  k1dt   <<<dim3(1024),  dim3(256), 0, stream>>>(x, dt_bias, wsb);
  k12_projconv<<<dim3(1024), dim3(256), 0, stream>>>(x, conv_w, conv_b, wsb);
  k3_cum <<<dim3(2048),  dim3(128), 0, stream>>>(A_log, wsb);
  k4a_cb <<<dim3(512),   dim3(256), 0, stream>>>(wsb);
  k4t_bt <<<dim3(128),   dim3(256), 0, stream>>>(wsb);
  k4s_states<<<dim3(2048), dim3(256), 0, stream>>>(wsb);
  k5_scan<<<dim3(1024),  dim3(256), 0, stream>>>(wsb);
  k4y_out<<<dim3(2048),  dim3(256), 0, stream>>>(Dp, wsb);
  k7_final<<<dim3(512),  dim3(256), 0, stream>>>(x, wsb, out);
}

// Round 5
// 155.027 us; speedup vs baseline: 3.8330x; 1.2266x over previous
//
#include <hip/hip_runtime.h>

typedef short short8 __attribute__((ext_vector_type(8)));
typedef float f32x4 __attribute__((ext_vector_type(4)));
typedef unsigned short ushort;
typedef unsigned int uint;

#define MFMA16(a,b,c) __builtin_amdgcn_mfma_f32_16x16x32_bf16(a,b,c,0,0,0)
#define DPROJ 1552

// ---- workspace byte offsets ----
constexpr size_t OFF_M    = 0;                         // 3*1552 f32
constexpr size_t OFF_CB_B = 0x5000;                    // 1552 f32
constexpr size_t OFF_WT   = 0x8000;                    // 128*512 bf16
constexpr size_t OFF_XT   = 0x30000;                   // [bc128][h16][grp16][p32][e8] u16 = 16 MB
constexpr size_t OFF_DT   = OFF_XT  + 16777216ull;     // 16384*16 f32
constexpr size_t OFF_BCM  = OFF_DT  + 1048576ull;      // [row][512] u16 (B|C)
constexpr size_t OFF_CUM  = OFF_BCM + 16777216ull;     // 2048*128 f32
constexpr size_t OFF_CDC  = OFF_CUM + 1048576ull;      // 2048 f32
constexpr size_t OFF_CBT  = OFF_CDC + 8192ull;         // [bc][grp16][t128][e8] u16 = 4 MB
constexpr size_t OFF_BT   = OFF_CBT + 4194304ull;      // [bc][grp16][n256][e8] u16 = 8 MB
constexpr size_t OFF_ST   = OFF_BT  + 8388608ull;      // [bi][grp32][p32][e8] u16 = 32 MB
constexpr size_t OFF_Y    = OFF_ST  + 33554432ull;     // 16384*512 f32

__device__ __forceinline__ float sigm(float x){ return 1.0f/(1.0f + __expf(-x)); }
__device__ __forceinline__ ushort f2bf(float f){
  union { float f; uint u; } c; c.f = f;
  uint u = c.u;
  return (ushort)((u + 0x7FFFu + ((u>>16)&1u)) >> 16);
}
__device__ __forceinline__ float bf2f(ushort h){
  union { uint u; float f; } c; c.u = ((uint)h)<<16;
  return c.f;
}
// XCD swizzle for 2048-block grids: all 16 heads of one (b,c) on one XCD
__device__ __forceinline__ void swz2048(int p, int& bc, int& h){
  int xcd = p & 7, slot = p >> 3;
  bc = xcd*16 + (slot >> 4);
  h  = slot & 15;
}

// ---------------- K0: fuse fc0 into in_proj ----------------
__global__ __launch_bounds__(256) void k0_prep(const float* __restrict__ fc0_w,
                                               const float* __restrict__ fc0_b,
                                               const float* __restrict__ W,
                                               char* __restrict__ wsb){
  float* Mo = (float*)(wsb + OFF_M);
  float* Co = (float*)(wsb + OFF_CB_B);
  int j = blockIdx.x*256 + threadIdx.x;
  if (j >= DPROJ) return;
  float m0=0.f,m1=0.f,m2=0.f,cc=0.f;
  for (int d=0; d<128; ++d){
    float w = W[(size_t)d*DPROJ + j];
    m0 = fmaf(fc0_w[d],     w, m0);
    m1 = fmaf(fc0_w[128+d], w, m1);
    m2 = fmaf(fc0_w[256+d], w, m2);
    cc = fmaf(fc0_b[d],     w, cc);
  }
  Mo[j] = m0; Mo[DPROJ + j] = m1; Mo[2*DPROJ + j] = m2;
  Co[j] = cc;
}

// ---------------- K0b: WoutT'[d][i] = norm_w[i]*Wout[i][d] ----------------------
__global__ __launch_bounds__(256) void k0b_wt(const float* __restrict__ norm_w,
                                              const float* __restrict__ Wout,
                                              char* __restrict__ wsb){
  ushort* WT = (ushort*)(wsb + OFF_WT);
  int d = blockIdx.x;
  for (int i = threadIdx.x; i < 512; i += 256)
    WT[(size_t)d*512 + i] = f2bf(norm_w[i]*Wout[(size_t)i*128 + d]);
}

// ---------------- K1dt: dt = softplus(proj + bias) ------------------------------
__global__ __launch_bounds__(256) void k1dt(const float* __restrict__ x,
                                            const float* __restrict__ dt_bias,
                                            char* __restrict__ wsb){
  int idx = blockIdx.x*256 + threadIdx.x;   // 262144
  int r = idx >> 4, hh = idx & 15;
  int b = r >> 13, l = r & 8191;
  int hp, wv;
  if (l < 4096){ hp = l>>6; wv = l&63; }
  else { int l2 = l-4096; hp = 63-(l2>>6); wv = 63-(l2&63); }
  const float* xb = x + (size_t)b*12288;
  float x0 = xb[hp*64+wv], x1 = xb[4096+hp*64+wv], x2 = xb[8192+hp*64+wv];
  const float* M  = (const float*)(wsb + OFF_M);
  const float* Cc = (const float*)(wsb + OFF_CB_B);
  int j = 1536 + hh;
  float v = Cc[j];
  v = fmaf(x0, M[j], v);
  v = fmaf(x1, M[DPROJ+j], v);
  v = fmaf(x2, M[2*DPROJ+j], v);
  float t = v + dt_bias[hh];
  ((float*)(wsb+OFF_DT))[(size_t)r*16+hh] = (t > 20.f) ? t : log1pf(__expf(t));
}

// ------ K12: fused proj+causal conv(4)+silu -> xT tiled / BC row-major ----------
__device__ __forceinline__ void proj8(int li, const float* __restrict__ xb,
                                      const float* m0, const float* m1, const float* m2,
                                      const float* c8, float* dst){
  if (li < 0){
    #pragma unroll
    for (int j=0;j<8;++j) dst[j] = 0.f;
    return;
  }
  int hh, wv;
  if (li < 4096){ hh = li>>6; wv = li&63; }
  else { int l2 = li-4096; hh = 63-(l2>>6); wv = 63-(l2&63); }
  float x0 = xb[hh*64+wv], x1 = xb[4096+hh*64+wv], x2 = xb[8192+hh*64+wv];
  #pragma unroll
  for (int j=0;j<8;++j)
    dst[j] = fmaf(x2, m2[j], fmaf(x1, m1[j], fmaf(x0, m0[j], c8[j])));
}

__device__ __forceinline__ void conv8(const float* cb8, const float* cw0, const float* cw1,
                                      const float* cw2, const float* cw3,
                                      const float* wA, const float* wB,
                                      const float* wC, const float* wD, ushort* o){
  #pragma unroll
  for (int j=0;j<8;++j){
    float a = cb8[j];
    a = fmaf(wA[j], cw0[j], a);
    a = fmaf(wB[j], cw1[j], a);
    a = fmaf(wC[j], cw2[j], a);
    a = fmaf(wD[j], cw3[j], a);
    o[j] = f2bf(a * sigm(a));
  }
}
__device__ __forceinline__ void cp8(ushort* d, const ushort* s){
  #pragma unroll
  for (int j=0;j<8;++j) d[j] = s[j];
}

__global__ __launch_bounds__(256) void k12_projconv(const float* __restrict__ x,
                                                    const float* __restrict__ conv_w,
                                                    const float* __restrict__ conv_b,
                                                    char* __restrict__ wsb){
  int tid = threadIdx.x;
  int cg = tid & 127, rl = tid >> 7;
  int row0 = blockIdx.x*16 + rl*8;        // 1024 blocks, 16 rows each
  int b = row0 >> 13, l0 = row0 & 8191;
  const float* M  = (const float*)(wsb + OFF_M);
  const float* Cc = (const float*)(wsb + OFF_CB_B);
  const float* xb = x + (size_t)b*12288;
  int ch0 = cg*8, j0 = 512 + ch0;
  float m0[8],m1[8],m2[8],c8[8],cw0[8],cw1[8],cw2[8],cw3[8],cb8[8];
  #pragma unroll
  for (int j=0;j<8;++j){
    m0[j]=M[j0+j]; m1[j]=M[DPROJ+j0+j]; m2[j]=M[2*DPROJ+j0+j]; c8[j]=Cc[j0+j];
    cw0[j]=conv_w[(ch0+j)*4+0]; cw1[j]=conv_w[(ch0+j)*4+1];
    cw2[j]=conv_w[(ch0+j)*4+2]; cw3[j]=conv_w[(ch0+j)*4+3];
    cb8[j]=conv_b[ch0+j];
  }
  bool is_xs = (ch0 < 512);
  ushort* bcmp = (ushort*)(wsb + OFF_BCM);
  int chb = ch0 - 512;
  uint colw[8][4];        // [p-lane j][row-pair] packed bf16x2, static idx only
  ushort oprev[8];
  float w0[8],w1[8],w2[8],w3[8];
  ushort o[8];
  proj8(l0-3, xb, m0,m1,m2,c8, w1);
  proj8(l0-2, xb, m0,m1,m2,c8, w2);
  proj8(l0-1, xb, m0,m1,m2,c8, w3);

#define ROW_EVEN(R, WN, WA, WB, WC)                                          \
  proj8(l0+R, xb, m0,m1,m2,c8, WN);                                          \
  conv8(cb8,cw0,cw1,cw2,cw3, WA,WB,WC,WN, o);                                \
  if (is_xs) cp8(oprev, o);                                                  \
  else *(uint4*)(bcmp + (size_t)(row0+R)*512 + chb) = *(uint4*)o;
#define ROW_ODD(R, WN, WA, WB, WC)                                           \
  proj8(l0+R, xb, m0,m1,m2,c8, WN);                                          \
  conv8(cb8,cw0,cw1,cw2,cw3, WA,WB,WC,WN, o);                                \
  if (is_xs){ _Pragma("unroll")                                              \
    for (int j=0;j<8;++j) colw[j][(R)>>1] = (uint)oprev[j] | ((uint)o[j]<<16); } \
  else *(uint4*)(bcmp + (size_t)(row0+R)*512 + chb) = *(uint4*)o;

  ROW_EVEN(0, w0, w1,w2,w3)
  ROW_ODD (1, w1, w2,w3,w0)
  ROW_EVEN(2, w2, w3,w0,w1)
  ROW_ODD (3, w3, w0,w1,w2)
  ROW_EVEN(4, w0, w1,w2,w3)
  ROW_ODD (5, w1, w2,w3,w0)
  ROW_EVEN(6, w2, w3,w0,w1)
  ROW_ODD (7, w3, w0,w1,w2)
#undef ROW_EVEN
#undef ROW_ODD

  if (is_xs){
    int h = ch0>>5, p0 = ch0&31;
    int bc = row0>>7, grp = (row0&127)>>3;
    ushort* dst = (ushort*)(wsb+OFF_XT) + (((size_t)(bc*16+h)*16 + grp)*32)*8;
    #pragma unroll
    for (int j=0;j<8;++j){
      uint4 v; v.x = colw[j][0]; v.y = colw[j][1]; v.z = colw[j][2]; v.w = colw[j][3];
      *(uint4*)(dst + (size_t)(p0+j)*8) = v;
    }
  }
}

// ---------------- K3: per (b,c,h) inclusive cumsum of dt*A ----------------------
__global__ __launch_bounds__(128) void k3_cum(const float* __restrict__ A_log,
                                              char* __restrict__ wsb){
  int bi = blockIdx.x;                    // (b*64+c)*16 + h
  int h = bi & 15;
  int t = threadIdx.x;
  __shared__ float s[128];
  float A = -__expf(A_log[h]);
  const float* dtp = (const float*)(wsb + OFF_DT);
  size_t row = (size_t)(bi>>4)*128 + t;
  float a = dtp[row*16 + h] * A;
  s[t] = a; __syncthreads();
  for (int off=1; off<128; off<<=1){
    float v = (t>=off) ? s[t-off] : 0.f;
    __syncthreads();
    s[t] += v;
    __syncthreads();
  }
  ((float*)(wsb + OFF_CUM))[(size_t)bi*128 + t] = s[t];
  if (t==127) ((float*)(wsb + OFF_CDC))[bi] = __expf(s[127]);
}

// ---------------- K4a: CB = C·B^T via MFMA -> cbt tiled [grp][t][e] -------------
__global__ __launch_bounds__(256) void k4a_cb(char* __restrict__ wsb){
  int bi = blockIdx.x;                    // (b*64+c)*4 + squad
  int sq = bi & 3; int bc = bi >> 2;
  __shared__ __align__(16) char sC[16384];   // C[128][64] bf16 swizzled rows(128B)
  __shared__ __align__(16) char sB[4096];    // B[32][64]  bf16 swizzled
  const ushort* bcm = (const ushort*)(wsb + OFF_BCM);
  ushort* cbtT = (ushort*)(wsb + OFF_CBT) + (size_t)bc*16384;
  size_t rb = (size_t)bc*128;
  int tid = threadIdx.x;
  int lane = tid&63, wid = tid>>6, l15 = lane&15, l4 = lane>>4;
  int s_base = sq*32;
  f32x4 acc[2][2] = {};
  for (int nt = 0; nt < 4; ++nt){
    int n0 = nt*64;
    __syncthreads();
    for (int idx = tid; idx < 1024; idx += 256){
      int t = idx>>3, c = idx&7;
      uint4 v = *(const uint4*)(bcm + (rb+t)*512 + 256 + n0 + c*8);
      *(uint4*)(sC + ((t*128 + c*16) ^ ((t&7)<<4))) = v;
    }
    {
      int idx = tid;
      int s = idx>>3, c = idx&7;
      uint4 v = *(const uint4*)(bcm + (rb+s_base+s)*512 + n0 + c*8);
      *(uint4*)(sB + ((s*128 + c*16) ^ ((s&7)<<4))) = v;
    }
    __syncthreads();
    #pragma unroll
    for (int ks = 0; ks < 2; ++ks){
      int kb = ks*64 + l4*16;
      int t0 = wid*32 + l15, t1 = t0 + 16;
      short8 a0 = *(const short8*)(sC + ((t0*128 + kb) ^ ((t0&7)<<4)));
      short8 a1 = *(const short8*)(sC + ((t1*128 + kb) ^ ((t1&7)<<4)));
      short8 b0 = *(const short8*)(sB + ((l15*128 + kb) ^ ((l15&7)<<4)));
      short8 b1 = *(const short8*)(sB + (((16+l15)*128 + kb) ^ (((16+l15)&7)<<4)));
      acc[0][0] = MFMA16(a0,b0,acc[0][0]);
      acc[0][1] = MFMA16(a0,b1,acc[0][1]);
      acc[1][0] = MFMA16(a1,b0,acc[1][0]);
      acc[1][1] = MFMA16(a1,b1,acc[1][1]);
    }
  }
  #pragma unroll
  for (int mt=0; mt<2; ++mt)
  #pragma unroll
  for (int st=0; st<2; ++st)
  #pragma unroll
  for (int r=0; r<4; ++r){
    int t = wid*32 + mt*16 + l4*4 + r;
    int s = s_base + st*16 + l15;
    cbtT[(size_t)((s>>3)*128 + t)*8 + (s&7)] = f2bf(acc[mt][st][r]);
  }
}

// ---------------- K4t: bt tiled [grp16][n256][e8] per bc -------------------------
__global__ __launch_bounds__(256) void k4t_bt(char* __restrict__ wsb){
  int bc = blockIdx.x; int n = threadIdx.x;
  const ushort* bcm = (const ushort*)(wsb + OFF_BCM);
  size_t rb = (size_t)bc*128;
  uint pk[64];
  #pragma unroll
  for (int s2 = 0; s2 < 64; ++s2){
    uint lo = bcm[(rb + 2*s2  )*512 + n];
    uint hi = bcm[(rb + 2*s2+1)*512 + n];
    pk[s2] = lo | (hi<<16);
  }
  ushort* btb = (ushort*)(wsb + OFF_BT) + (size_t)bc*32768;
  #pragma unroll
  for (int grp=0; grp<16; ++grp){
    uint4 v; v.x = pk[grp*4]; v.y = pk[grp*4+1]; v.z = pk[grp*4+2]; v.w = pk[grp*4+3];
    *(uint4*)(btb + (size_t)(grp*256 + n)*8) = v;
  }
}

// -------- K4s: states = (x*w)^T @ B, frags direct from global -------------------
__global__ __launch_bounds__(256) void k4s_states(char* __restrict__ wsb){
  int bc, h; swz2048(blockIdx.x, bc, h);
  int bi = bc*16 + h;
  __shared__ float sW[128];
  const ushort* xt  = (const ushort*)(wsb + OFF_XT) + (size_t)bi*4096;
  const ushort* btb = (const ushort*)(wsb + OFF_BT) + (size_t)bc*32768;
  const float* cum  = (const float*)(wsb + OFF_CUM) + (size_t)bi*128;
  const float* dtp  = (const float*)(wsb + OFF_DT);
  ushort* st = (ushort*)(wsb + OFF_ST) + (size_t)bi*8192;
  size_t rb = (size_t)bc*128;
  int tid = threadIdx.x;
  if (tid < 128){
    float c127 = cum[127];
    sW[tid] = __expf(c127 - cum[tid]) * dtp[(rb+tid)*16 + h];
  }
  __syncthreads();
  int lane = tid&63, wid = tid>>6, l15 = lane&15, l4 = lane>>4;
  f32x4 acc2[2][4] = {};
  #pragma unroll
  for (int ks = 0; ks < 4; ++ks){
    int grp = ks*4 + l4;
    const float* wp = sW + grp*8;
    short8 ra0 = *(const short8*)(xt + (size_t)(grp*32 + l15)*8);
    short8 ra1 = *(const short8*)(xt + (size_t)(grp*32 + 16 + l15)*8);
    short8 a0, a1;
    #pragma unroll
    for (int j=0;j<8;++j){
      a0[j] = (short)f2bf(bf2f((ushort)ra0[j]) * wp[j]);
      a1[j] = (short)f2bf(bf2f((ushort)ra1[j]) * wp[j]);
    }
    #pragma unroll
    for (int ntl = 0; ntl < 4; ++ntl){
      int n = wid*64 + ntl*16 + l15;
      short8 b = *(const short8*)(btb + (size_t)(grp*256 + n)*8);
      acc2[0][ntl] = MFMA16(a0,b,acc2[0][ntl]);
      acc2[1][ntl] = MFMA16(a1,b,acc2[1][ntl]);
    }
  }
  #pragma unroll
  for (int mt=0; mt<2; ++mt)
  #pragma unroll
  for (int ntl=0; ntl<4; ++ntl)
  #pragma unroll
  for (int r=0; r<4; ++r){
    int p = mt*16 + l4*4 + r;
    int n = wid*64 + ntl*16 + l15;
    st[(size_t)((n>>3)*32 + p)*8 + (n&7)] = f2bf(acc2[mt][ntl][r]);
  }
}

// ---------------- K5: sequential chunk scan (tiled ST, in place) ----------------
__global__ __launch_bounds__(256) void k5_scan(char* __restrict__ wsb){
  int g = blockIdx.x*256 + threadIdx.x;   // 262144 threads
  int l = g & 63;
  int e = l & 7, plow = l >> 3;
  int up = g >> 6;
  int p = (up & 3)*8 + plow; up >>= 2;
  int grp = up & 31; up >>= 5;
  int h = up & 15; int b = up >> 4;
  int off = (grp*32 + p)*8 + e;
  ushort* st = (ushort*)(wsb + OFF_ST);
  const float* cdc = (const float*)(wsb + OFF_CDC);
  float S = 0.f;
  for (int c=0; c<64; ++c){
    int bi = (b*64+c)*16 + h;
    size_t idx = (size_t)bi*8192 + off;
    float v = bf2f(st[idx]);
    st[idx] = f2bf(S);
    S = fmaf(S, cdc[bi], v);
  }
}

// -------- K4y: y = attn@x + exp(cum)*C@prev + D*x, frags direct from global -----
__global__ __launch_bounds__(256) void k4y_out(const float* __restrict__ Dp,
                                               char* __restrict__ wsb){
  int bc, h; swz2048(blockIdx.x, bc, h);
  int bi = bc*16 + h;
  __shared__ float sCum[128], sDt[128], sE[128];
  const ushort* cbt = (const ushort*)(wsb + OFF_CBT) + (size_t)bc*16384;
  const ushort* xt  = (const ushort*)(wsb + OFF_XT) + (size_t)bi*4096;
  const ushort* bcm = (const ushort*)(wsb + OFF_BCM);
  const ushort* prev= (const ushort*)(wsb + OFF_ST) + (size_t)bi*8192;
  const float* cum  = (const float*)(wsb + OFF_CUM) + (size_t)bi*128;
  const float* dtp  = (const float*)(wsb + OFF_DT);
  float* Y = (float*)(wsb + OFF_Y);
  size_t rb = (size_t)bc*128;
  int tid = threadIdx.x;
  if (tid < 128){
    float cv = cum[tid];
    sCum[tid] = cv;
    sDt[tid]  = dtp[(rb+tid)*16 + h];
    sE[tid]   = __expf(cv);
  }
  __syncthreads();
  int lane = tid&63, wid = tid>>6, l15 = lane&15, l4 = lane>>4;
  int t0 = wid*32 + l15, t1 = t0 + 16;
  float ct0 = sCum[t0], ct1 = sCum[t1];
  // ---- y_intra: A = CB*decay*dt built in-register, B = xT frags ----
  f32x4 acc[2][2] = {};
  #pragma unroll
  for (int ks = 0; ks < 4; ++ks){
    int grp = ks*4 + l4;
    int s0 = grp*8;
    short8 ra0 = *(const short8*)(cbt + (size_t)(grp*128 + t0)*8);
    short8 ra1 = *(const short8*)(cbt + (size_t)(grp*128 + t1)*8);
    short8 a0, a1;
    #pragma unroll
    for (int j=0;j<8;++j){
      int s = s0 + j;
      float cs = sCum[s], ds = sDt[s];
      float e0 = __expf(fminf(ct0 - cs, 0.f)) * ds;
      float e1 = __expf(fminf(ct1 - cs, 0.f)) * ds;
      float v0 = (t0 >= s) ? bf2f((ushort)ra0[j]) * e0 : 0.f;
      float v1 = (t1 >= s) ? bf2f((ushort)ra1[j]) * e1 : 0.f;
      a0[j] = (short)f2bf(v0);
      a1[j] = (short)f2bf(v1);
    }
    short8 b0 = *(const short8*)(xt + (size_t)(grp*32 + l15)*8);
    short8 b1 = *(const short8*)(xt + (size_t)(grp*32 + 16 + l15)*8);
    acc[0][0] = MFMA16(a0,b0,acc[0][0]);
    acc[0][1] = MFMA16(a0,b1,acc[0][1]);
    acc[1][0] = MFMA16(a1,b0,acc[1][0]);
    acc[1][1] = MFMA16(a1,b1,acc[1][1]);
  }
  // ---- y_inter = C @ prev^T : K=n(256) ----
  f32x4 acc2[2][2] = {};
  #pragma unroll
  for (int ks = 0; ks < 8; ++ks){
    int koff = ks*32 + l4*8;
    int grp = ks*4 + l4;
    short8 a0 = *(const short8*)(bcm + (rb+t0)*512 + 256 + koff);
    short8 a1 = *(const short8*)(bcm + (rb+t1)*512 + 256 + koff);
    short8 b0 = *(const short8*)(prev + (size_t)(grp*32 + l15)*8);
    short8 b1 = *(const short8*)(prev + (size_t)(grp*32 + 16 + l15)*8);
    acc2[0][0] = MFMA16(a0,b0,acc2[0][0]);
    acc2[0][1] = MFMA16(a0,b1,acc2[0][1]);
    acc2[1][0] = MFMA16(a1,b0,acc2[1][0]);
    acc2[1][1] = MFMA16(a1,b1,acc2[1][1]);
  }
  float Dh = Dp[h];
  #pragma unroll
  for (int mt=0; mt<2; ++mt){
    int tb = wid*32 + mt*16 + l4*4;
    int tg = tb>>3, e0 = tb&7;
    #pragma unroll
    for (int nt=0; nt<2; ++nt){
      int p = nt*16 + l15;
      ushort xv[4];
      *(uint2*)xv = *(const uint2*)(xt + (size_t)(tg*32 + p)*8 + e0);
      #pragma unroll
      for (int r=0; r<4; ++r){
        int t = tb + r;
        Y[(rb+t)*512 + h*32 + p] = acc[mt][nt][r] + sE[t]*acc2[mt][nt][r] + Dh*bf2f(xv[r]);
      }
    }
  }
}

// ---------------- K7: gate(silu(z)) -> RMS -> out_proj (MFMA) -------------------
__global__ __launch_bounds__(256) void k7_final(const float* __restrict__ x,
                                                char* __restrict__ wsb,
                                                float* __restrict__ out){
  int r0 = blockIdx.x*32;                  // 512 blocks
  __shared__ __align__(16) char sG[32768]; // G[32][512] bf16 rows 1024B, swizzled
  __shared__ float sScale[32];
  const float* Y  = (const float*)(wsb + OFF_Y);
  const float* M  = (const float*)(wsb + OFF_M);
  const float* Cb = (const float*)(wsb + OFF_CB_B);
  const ushort* WT = (const ushort*)(wsb + OFF_WT);
  int tid = threadIdx.x;
  int r = tid>>3, li = tid&7;
  int row = r0 + r; int b = row>>13, l = row & 8191;
  int hh, wv;
  if (l < 4096){ hh = l>>6; wv = l&63; }
  else { int l2 = l-4096; hh = 63-(l2>>6); wv = 63-(l2&63); }
  const float* xb = x + (size_t)b*12288;
  float x0 = xb[hh*64+wv], x1 = xb[4096+hh*64+wv], x2 = xb[8192+hh*64+wv];
  float sq = 0.f;
  for (int k = 0; k < 64; ++k){
    int i = li + 8*k;
    float z = Cb[i];
    z = fmaf(x0, M[i], z);
    z = fmaf(x1, M[DPROJ+i], z);
    z = fmaf(x2, M[2*DPROJ+i], z);
    float y = Y[(size_t)row*512 + i];
    float g = y * z * sigm(z);
    sq = fmaf(g, g, sq);
    *(ushort*)(sG + ((r*1024 + i*2) ^ ((r&7)<<4))) = f2bf(g);
  }
  sq += __shfl_xor(sq, 1, 64);
  sq += __shfl_xor(sq, 2, 64);
  sq += __shfl_xor(sq, 4, 64);
  if (li == 0) sScale[r] = rsqrtf(sq*(1.f/512.f) + 1e-5f);
  __syncthreads();
  int lane = tid&63, wid = tid>>6, l15 = lane&15, l4 = lane>>4;
  f32x4 acc[2][2] = {};
  #pragma unroll
  for (int ks = 0; ks < 16; ++ks){
    int kb = ks*64 + l4*16;
    int rr0 = l15, rr1 = 16+l15;
    short8 a0 = *(const short8*)(sG + ((rr0*1024 + kb) ^ ((rr0&7)<<4)));
    short8 a1 = *(const short8*)(sG + ((rr1*1024 + kb) ^ ((rr1&7)<<4)));
    int koff = ks*32 + l4*8;
    short8 b0 = *(const short8*)(WT + (size_t)(wid*32 + l15)*512 + koff);
    short8 b1 = *(const short8*)(WT + (size_t)(wid*32 + 16 + l15)*512 + koff);
    acc[0][0] = MFMA16(a0,b0,acc[0][0]);
    acc[0][1] = MFMA16(a0,b1,acc[0][1]);
    acc[1][0] = MFMA16(a1,b0,acc[1][0]);
    acc[1][1] = MFMA16(a1,b1,acc[1][1]);
  }
  #pragma unroll
  for (int mt=0; mt<2; ++mt)
  #pragma unroll
  for (int nt=0; nt<2; ++nt)
  #pragma unroll
  for (int r4=0; r4<4; ++r4){
    int rr = mt*16 + l4*4 + r4;
    int d = wid*32 + nt*16 + l15;
    out[(size_t)(r0+rr)*128 + d] = acc[mt][nt][r4] * sScale[rr];
  }
}

extern "C" void kernel_launch(void* const* d_in, const int* in_sizes, int n_in,
                              void* d_out, int out_size, void* d_ws, size_t ws_size,
                              hipStream_t stream) {
  const float* x         = (const float*)d_in[0];
  const float* fc0_w     = (const float*)d_in[1];
  const float* fc0_b     = (const float*)d_in[2];
  const float* in_proj_w = (const float*)d_in[3];
  const float* conv_w    = (const float*)d_in[4];
  const float* conv_b    = (const float*)d_in[5];
  const float* dt_bias   = (const float*)d_in[6];
  const float* A_log     = (const float*)d_in[7];
  const float* Dp        = (const float*)d_in[8];
  const float* norm_w    = (const float*)d_in[9];
  const float* out_proj_w= (const float*)d_in[10];
  char* wsb  = (char*)d_ws;
  float* out = (float*)d_out;

  k0_prep<<<dim3(7),     dim3(256), 0, stream>>>(fc0_w, fc0_b, in_proj_w, wsb);
  k0b_wt <<<dim3(128),   dim3(256), 0, stream>>>(norm_w, out_proj_w, wsb);
  k1dt   <<<dim3(1024),  dim3(256), 0, stream>>>(x, dt_bias, wsb);
  k12_projconv<<<dim3(1024), dim3(256), 0, stream>>>(x, conv_w, conv_b, wsb);
  k3_cum <<<dim3(2048),  dim3(128), 0, stream>>>(A_log, wsb);
  k4a_cb <<<dim3(512),   dim3(256), 0, stream>>>(wsb);
  k4t_bt <<<dim3(128),   dim3(256), 0, stream>>>(wsb);
  k4s_states<<<dim3(2048), dim3(256), 0, stream>>>(wsb);
  k5_scan<<<dim3(1024),  dim3(256), 0, stream>>>(wsb);
  k4y_out<<<dim3(2048),  dim3(256), 0, stream>>>(Dp, wsb);
  k7_final<<<dim3(512),  dim3(256), 0, stream>>>(x, wsb, out);
}

// Round 6
// 152.785 us; speedup vs baseline: 3.8893x; 1.0147x over previous
//
#include <hip/hip_runtime.h>

typedef short short8 __attribute__((ext_vector_type(8)));
typedef float f32x4 __attribute__((ext_vector_type(4)));
typedef unsigned short ushort;
typedef unsigned int uint;

#define MFMA16(a,b,c) __builtin_amdgcn_mfma_f32_16x16x32_bf16(a,b,c,0,0,0)
#define DPROJ 1552

// ---- workspace byte offsets ----
constexpr size_t OFF_M    = 0;                         // 3*1552 f32
constexpr size_t OFF_CB_B = 0x5000;                    // 1552 f32
constexpr size_t OFF_WT   = 0x8000;                    // 128*512 bf16
constexpr size_t OFF_XT   = 0x30000;                   // [bc128][h16][grp16][p32][e8] u16 = 16 MB
constexpr size_t OFF_DT   = OFF_XT  + 16777216ull;     // 16384*16 f32
constexpr size_t OFF_BCM  = OFF_DT  + 1048576ull;      // [row][512] u16 (B|C)
constexpr size_t OFF_CUM  = OFF_BCM + 16777216ull;     // 2048*128 f32
constexpr size_t OFF_CDC  = OFF_CUM + 1048576ull;      // 2048 f32
constexpr size_t OFF_CBT  = OFF_CDC + 8192ull;         // [bc][grp16][t128][e8] u16 = 4 MB
constexpr size_t OFF_BT   = OFF_CBT + 4194304ull;      // [bc][grp16][n256][e8] u16 = 8 MB
constexpr size_t OFF_ST   = OFF_BT  + 8388608ull;      // [bi][grp32][p32][e8] u16 = 32 MB
constexpr size_t OFF_Y    = OFF_ST  + 33554432ull;     // 16384*512 bf16 = 16.7 MB

__device__ __forceinline__ float sigm(float x){ return 1.0f/(1.0f + __expf(-x)); }
__device__ __forceinline__ ushort f2bf(float f){
  union { float f; uint u; } c; c.f = f;
  uint u = c.u;
  return (ushort)((u + 0x7FFFu + ((u>>16)&1u)) >> 16);
}
__device__ __forceinline__ float bf2f(ushort h){
  union { uint u; float f; } c; c.u = ((uint)h)<<16;
  return c.f;
}
// XCD swizzle for 2048-block grids: all 16 heads of one (b,c) on one XCD
__device__ __forceinline__ void swz2048(int p, int& bc, int& h){
  int xcd = p & 7, slot = p >> 3;
  bc = xcd*16 + (slot >> 4);
  h  = slot & 15;
}

// ---------------- K0: fuse fc0 into in_proj ----------------
__global__ __launch_bounds__(256) void k0_prep(const float* __restrict__ fc0_w,
                                               const float* __restrict__ fc0_b,
                                               const float* __restrict__ W,
                                               char* __restrict__ wsb){
  float* Mo = (float*)(wsb + OFF_M);
  float* Co = (float*)(wsb + OFF_CB_B);
  int j = blockIdx.x*256 + threadIdx.x;
  if (j >= DPROJ) return;
  float m0=0.f,m1=0.f,m2=0.f,cc=0.f;
  for (int d=0; d<128; ++d){
    float w = W[(size_t)d*DPROJ + j];
    m0 = fmaf(fc0_w[d],     w, m0);
    m1 = fmaf(fc0_w[128+d], w, m1);
    m2 = fmaf(fc0_w[256+d], w, m2);
    cc = fmaf(fc0_b[d],     w, cc);
  }
  Mo[j] = m0; Mo[DPROJ + j] = m1; Mo[2*DPROJ + j] = m2;
  Co[j] = cc;
}

// ---------------- K0b: WoutT'[d][i] = norm_w[i]*Wout[i][d] ----------------------
__global__ __launch_bounds__(256) void k0b_wt(const float* __restrict__ norm_w,
                                              const float* __restrict__ Wout,
                                              char* __restrict__ wsb){
  ushort* WT = (ushort*)(wsb + OFF_WT);
  int d = blockIdx.x;
  for (int i = threadIdx.x; i < 512; i += 256)
    WT[(size_t)d*512 + i] = f2bf(norm_w[i]*Wout[(size_t)i*128 + d]);
}

// ------ K12: fused proj+causal conv(4)+silu -> xT tiled / BC row-major ----------
__device__ __forceinline__ void proj8(int li, const float* __restrict__ xb,
                                      const float* m0, const float* m1, const float* m2,
                                      const float* c8, float* dst){
  if (li < 0){
    #pragma unroll
    for (int j=0;j<8;++j) dst[j] = 0.f;
    return;
  }
  int hh, wv;
  if (li < 4096){ hh = li>>6; wv = li&63; }
  else { int l2 = li-4096; hh = 63-(l2>>6); wv = 63-(l2&63); }
  float x0 = xb[hh*64+wv], x1 = xb[4096+hh*64+wv], x2 = xb[8192+hh*64+wv];
  #pragma unroll
  for (int j=0;j<8;++j)
    dst[j] = fmaf(x2, m2[j], fmaf(x1, m1[j], fmaf(x0, m0[j], c8[j])));
}

__device__ __forceinline__ void conv8(const float* cb8, const float* cw0, const float* cw1,
                                      const float* cw2, const float* cw3,
                                      const float* wA, const float* wB,
                                      const float* wC, const float* wD, ushort* o){
  #pragma unroll
  for (int j=0;j<8;++j){
    float a = cb8[j];
    a = fmaf(wA[j], cw0[j], a);
    a = fmaf(wB[j], cw1[j], a);
    a = fmaf(wC[j], cw2[j], a);
    a = fmaf(wD[j], cw3[j], a);
    o[j] = f2bf(a * sigm(a));
  }
}
__device__ __forceinline__ void cp8(ushort* d, const ushort* s){
  #pragma unroll
  for (int j=0;j<8;++j) d[j] = s[j];
}

__global__ __launch_bounds__(256) void k12_projconv(const float* __restrict__ x,
                                                    const float* __restrict__ conv_w,
                                                    const float* __restrict__ conv_b,
                                                    char* __restrict__ wsb){
  int tid = threadIdx.x;
  int cg = tid & 127, rl = tid >> 7;
  int row0 = blockIdx.x*16 + rl*8;        // 1024 blocks, 16 rows each
  int b = row0 >> 13, l0 = row0 & 8191;
  const float* M  = (const float*)(wsb + OFF_M);
  const float* Cc = (const float*)(wsb + OFF_CB_B);
  const float* xb = x + (size_t)b*12288;
  int ch0 = cg*8, j0 = 512 + ch0;
  float m0[8],m1[8],m2[8],c8[8],cw0[8],cw1[8],cw2[8],cw3[8],cb8[8];
  #pragma unroll
  for (int j=0;j<8;++j){
    m0[j]=M[j0+j]; m1[j]=M[DPROJ+j0+j]; m2[j]=M[2*DPROJ+j0+j]; c8[j]=Cc[j0+j];
    cw0[j]=conv_w[(ch0+j)*4+0]; cw1[j]=conv_w[(ch0+j)*4+1];
    cw2[j]=conv_w[(ch0+j)*4+2]; cw3[j]=conv_w[(ch0+j)*4+3];
    cb8[j]=conv_b[ch0+j];
  }
  bool is_xs = (ch0 < 512);
  ushort* bcmp = (ushort*)(wsb + OFF_BCM);
  int chb = ch0 - 512;
  uint colw[8][4];        // [p-lane j][row-pair] packed bf16x2, static idx only
  ushort oprev[8];
  float w0[8],w1[8],w2[8],w3[8];
  ushort o[8];
  proj8(l0-3, xb, m0,m1,m2,c8, w1);
  proj8(l0-2, xb, m0,m1,m2,c8, w2);
  proj8(l0-1, xb, m0,m1,m2,c8, w3);

#define ROW_EVEN(R, WN, WA, WB, WC)                                          \
  proj8(l0+R, xb, m0,m1,m2,c8, WN);                                          \
  conv8(cb8,cw0,cw1,cw2,cw3, WA,WB,WC,WN, o);                                \
  if (is_xs) cp8(oprev, o);                                                  \
  else *(uint4*)(bcmp + (size_t)(row0+R)*512 + chb) = *(uint4*)o;
#define ROW_ODD(R, WN, WA, WB, WC)                                           \
  proj8(l0+R, xb, m0,m1,m2,c8, WN);                                          \
  conv8(cb8,cw0,cw1,cw2,cw3, WA,WB,WC,WN, o);                                \
  if (is_xs){ _Pragma("unroll")                                              \
    for (int j=0;j<8;++j) colw[j][(R)>>1] = (uint)oprev[j] | ((uint)o[j]<<16); } \
  else *(uint4*)(bcmp + (size_t)(row0+R)*512 + chb) = *(uint4*)o;

  ROW_EVEN(0, w0, w1,w2,w3)
  ROW_ODD (1, w1, w2,w3,w0)
  ROW_EVEN(2, w2, w3,w0,w1)
  ROW_ODD (3, w3, w0,w1,w2)
  ROW_EVEN(4, w0, w1,w2,w3)
  ROW_ODD (5, w1, w2,w3,w0)
  ROW_EVEN(6, w2, w3,w0,w1)
  ROW_ODD (7, w3, w0,w1,w2)
#undef ROW_EVEN
#undef ROW_ODD

  if (is_xs){
    int h = ch0>>5, p0 = ch0&31;
    int bc = row0>>7, grp = (row0&127)>>3;
    ushort* dst = (ushort*)(wsb+OFF_XT) + (((size_t)(bc*16+h)*16 + grp)*32)*8;
    #pragma unroll
    for (int j=0;j<8;++j){
      uint4 v; v.x = colw[j][0]; v.y = colw[j][1]; v.z = colw[j][2]; v.w = colw[j][3];
      *(uint4*)(dst + (size_t)(p0+j)*8) = v;
    }
  }
}

// ------- K3: dt = softplus(proj+bias) fused + per (b,c,h) cumsum of dt*A --------
__global__ __launch_bounds__(128) void k3_cum(const float* __restrict__ x,
                                              const float* __restrict__ dt_bias,
                                              const float* __restrict__ A_log,
                                              char* __restrict__ wsb){
  int bi = blockIdx.x;                    // (b*64+c)*16 + h
  int h = bi & 15; int bc = bi >> 4;
  int t = threadIdx.x;
  int r = bc*128 + t;
  int b = r >> 13, l = r & 8191;
  int hp, wv;
  if (l < 4096){ hp = l>>6; wv = l&63; }
  else { int l2 = l-4096; hp = 63-(l2>>6); wv = 63-(l2&63); }
  const float* xb = x + (size_t)b*12288;
  float x0 = xb[hp*64+wv], x1 = xb[4096+hp*64+wv], x2 = xb[8192+hp*64+wv];
  const float* M  = (const float*)(wsb + OFF_M);
  const float* Cc = (const float*)(wsb + OFF_CB_B);
  int j = 1536 + h;
  float v = Cc[j];
  v = fmaf(x0, M[j], v);
  v = fmaf(x1, M[DPROJ+j], v);
  v = fmaf(x2, M[2*DPROJ+j], v);
  float tt = v + dt_bias[h];
  float dtv = (tt > 20.f) ? tt : log1pf(__expf(tt));
  ((float*)(wsb+OFF_DT))[(size_t)r*16 + h] = dtv;
  __shared__ float s[128];
  float A = -__expf(A_log[h]);
  s[t] = dtv * A; __syncthreads();
  for (int off=1; off<128; off<<=1){
    float sv = (t>=off) ? s[t-off] : 0.f;
    __syncthreads();
    s[t] += sv;
    __syncthreads();
  }
  ((float*)(wsb + OFF_CUM))[(size_t)bi*128 + t] = s[t];
  if (t==127) ((float*)(wsb + OFF_CDC))[bi] = __expf(s[127]);
}

// ------- K4a: CB = C·B^T via MFMA -> cbt tiled; also emits BT tiled -------------
__global__ __launch_bounds__(256) void k4a_cb(char* __restrict__ wsb){
  int bi = blockIdx.x;                    // (b*64+c)*4 + squad
  int sq = bi & 3; int bc = bi >> 2;
  __shared__ __align__(16) char sC[16384];   // C[128][64] bf16 swizzled rows(128B)
  __shared__ __align__(16) char sB[4096];    // B[32][64]  bf16 swizzled
  const ushort* bcm = (const ushort*)(wsb + OFF_BCM);
  ushort* cbtT = (ushort*)(wsb + OFF_CBT) + (size_t)bc*16384;
  ushort* btb  = (ushort*)(wsb + OFF_BT)  + (size_t)bc*32768;
  size_t rb = (size_t)bc*128;
  int tid = threadIdx.x;
  int lane = tid&63, wid = tid>>6, l15 = lane&15, l4 = lane>>4;
  int s_base = sq*32;
  f32x4 acc[2][2] = {};
  for (int nt = 0; nt < 4; ++nt){
    int n0 = nt*64;
    __syncthreads();
    for (int idx = tid; idx < 1024; idx += 256){
      int t = idx>>3, c = idx&7;
      uint4 v = *(const uint4*)(bcm + (rb+t)*512 + 256 + n0 + c*8);
      *(uint4*)(sC + ((t*128 + c*16) ^ ((t&7)<<4))) = v;
    }
    {
      int idx = tid;
      int s = idx>>3, c = idx&7;
      uint4 v = *(const uint4*)(bcm + (rb+s_base+s)*512 + n0 + c*8);
      *(uint4*)(sB + ((s*128 + c*16) ^ ((s&7)<<4))) = v;
    }
    __syncthreads();
    // emit BT tile for this (sq, nt): grp in [sq*4, sq*4+4), n in [n0, n0+64)
    {
      int grp_l = tid>>6, n_l = tid&63;
      ushort o[8];
      #pragma unroll
      for (int sj=0; sj<8; ++sj){
        int sl = grp_l*8 + sj;
        o[sj] = *(const ushort*)(sB + ((sl*128 + n_l*2) ^ ((sl&7)<<4)));
      }
      *(uint4*)(btb + (size_t)((sq*4+grp_l)*256 + n0 + n_l)*8) = *(uint4*)o;
    }
    #pragma unroll
    for (int ks = 0; ks < 2; ++ks){
      int kb = ks*64 + l4*16;
      int t0 = wid*32 + l15, t1 = t0 + 16;
      short8 a0 = *(const short8*)(sC + ((t0*128 + kb) ^ ((t0&7)<<4)));
      short8 a1 = *(const short8*)(sC + ((t1*128 + kb) ^ ((t1&7)<<4)));
      short8 b0 = *(const short8*)(sB + ((l15*128 + kb) ^ ((l15&7)<<4)));
      short8 b1 = *(const short8*)(sB + (((16+l15)*128 + kb) ^ (((16+l15)&7)<<4)));
      acc[0][0] = MFMA16(a0,b0,acc[0][0]);
      acc[0][1] = MFMA16(a0,b1,acc[0][1]);
      acc[1][0] = MFMA16(a1,b0,acc[1][0]);
      acc[1][1] = MFMA16(a1,b1,acc[1][1]);
    }
  }
  #pragma unroll
  for (int mt=0; mt<2; ++mt)
  #pragma unroll
  for (int st=0; st<2; ++st)
  #pragma unroll
  for (int r=0; r<4; ++r){
    int t = wid*32 + mt*16 + l4*4 + r;
    int s = s_base + st*16 + l15;
    cbtT[(size_t)((s>>3)*128 + t)*8 + (s&7)] = f2bf(acc[mt][st][r]);
  }
}

// -------- K4s: states = (x*w)^T @ B, frags direct from global -------------------
__global__ __launch_bounds__(256) void k4s_states(char* __restrict__ wsb){
  int bc, h; swz2048(blockIdx.x, bc, h);
  int bi = bc*16 + h;
  __shared__ float sW[128];
  const ushort* xt  = (const ushort*)(wsb + OFF_XT) + (size_t)bi*4096;
  const ushort* btb = (const ushort*)(wsb + OFF_BT) + (size_t)bc*32768;
  const float* cum  = (const float*)(wsb + OFF_CUM) + (size_t)bi*128;
  const float* dtp  = (const float*)(wsb + OFF_DT);
  ushort* st = (ushort*)(wsb + OFF_ST) + (size_t)bi*8192;
  size_t rb = (size_t)bc*128;
  int tid = threadIdx.x;
  if (tid < 128){
    float c127 = cum[127];
    sW[tid] = __expf(c127 - cum[tid]) * dtp[(rb+tid)*16 + h];
  }
  __syncthreads();
  int lane = tid&63, wid = tid>>6, l15 = lane&15, l4 = lane>>4;
  f32x4 acc2[2][4] = {};
  #pragma unroll
  for (int ks = 0; ks < 4; ++ks){
    int grp = ks*4 + l4;
    const float* wp = sW + grp*8;
    short8 ra0 = *(const short8*)(xt + (size_t)(grp*32 + l15)*8);
    short8 ra1 = *(const short8*)(xt + (size_t)(grp*32 + 16 + l15)*8);
    short8 a0, a1;
    #pragma unroll
    for (int j=0;j<8;++j){
      a0[j] = (short)f2bf(bf2f((ushort)ra0[j]) * wp[j]);
      a1[j] = (short)f2bf(bf2f((ushort)ra1[j]) * wp[j]);
    }
    #pragma unroll
    for (int ntl = 0; ntl < 4; ++ntl){
      int n = wid*64 + ntl*16 + l15;
      short8 b = *(const short8*)(btb + (size_t)(grp*256 + n)*8);
      acc2[0][ntl] = MFMA16(a0,b,acc2[0][ntl]);
      acc2[1][ntl] = MFMA16(a1,b,acc2[1][ntl]);
    }
  }
  #pragma unroll
  for (int mt=0; mt<2; ++mt)
  #pragma unroll
  for (int ntl=0; ntl<4; ++ntl)
  #pragma unroll
  for (int r=0; r<4; ++r){
    int p = mt*16 + l4*4 + r;
    int n = wid*64 + ntl*16 + l15;
    st[(size_t)((n>>3)*32 + p)*8 + (n&7)] = f2bf(acc2[mt][ntl][r]);
  }
}

// ---------------- K5: sequential chunk scan (tiled ST, in place) ----------------
__global__ __launch_bounds__(256) void k5_scan(char* __restrict__ wsb){
  int g = blockIdx.x*256 + threadIdx.x;   // 262144 threads
  int l = g & 63;
  int e = l & 7, plow = l >> 3;
  int up = g >> 6;
  int p = (up & 3)*8 + plow; up >>= 2;
  int grp = up & 31; up >>= 5;
  int h = up & 15; int b = up >> 4;
  int off = (grp*32 + p)*8 + e;
  ushort* st = (ushort*)(wsb + OFF_ST);
  const float* cdc = (const float*)(wsb + OFF_CDC);
  float S = 0.f;
  for (int c=0; c<64; ++c){
    int bi = (b*64+c)*16 + h;
    size_t idx = (size_t)bi*8192 + off;
    float v = bf2f(st[idx]);
    st[idx] = f2bf(S);
    S = fmaf(S, cdc[bi], v);
  }
}

// -------- K4y: y = attn@x + exp(cum)*C@prev + D*x -> Y bf16 ---------------------
__global__ __launch_bounds__(256) void k4y_out(const float* __restrict__ Dp,
                                               char* __restrict__ wsb){
  int bc, h; swz2048(blockIdx.x, bc, h);
  int bi = bc*16 + h;
  __shared__ float sCum[128], sDt[128], sE[128];
  const ushort* cbt = (const ushort*)(wsb + OFF_CBT) + (size_t)bc*16384;
  const ushort* xt  = (const ushort*)(wsb + OFF_XT) + (size_t)bi*4096;
  const ushort* bcm = (const ushort*)(wsb + OFF_BCM);
  const ushort* prev= (const ushort*)(wsb + OFF_ST) + (size_t)bi*8192;
  const float* cum  = (const float*)(wsb + OFF_CUM) + (size_t)bi*128;
  const float* dtp  = (const float*)(wsb + OFF_DT);
  ushort* Yb = (ushort*)(wsb + OFF_Y);
  size_t rb = (size_t)bc*128;
  int tid = threadIdx.x;
  if (tid < 128){
    float cv = cum[tid];
    sCum[tid] = cv;
    sDt[tid]  = dtp[(rb+tid)*16 + h];
    sE[tid]   = __expf(cv);
  }
  __syncthreads();
  int lane = tid&63, wid = tid>>6, l15 = lane&15, l4 = lane>>4;
  int t0 = wid*32 + l15, t1 = t0 + 16;
  float ct0 = sCum[t0], ct1 = sCum[t1];
  // ---- y_intra: A = CB*decay*dt built in-register, B = xT frags ----
  f32x4 acc[2][2] = {};
  #pragma unroll
  for (int ks = 0; ks < 4; ++ks){
    int grp = ks*4 + l4;
    int s0 = grp*8;
    short8 ra0 = *(const short8*)(cbt + (size_t)(grp*128 + t0)*8);
    short8 ra1 = *(const short8*)(cbt + (size_t)(grp*128 + t1)*8);
    short8 a0, a1;
    #pragma unroll
    for (int j=0;j<8;++j){
      int s = s0 + j;
      float cs = sCum[s], ds = sDt[s];
      float e0 = __expf(fminf(ct0 - cs, 0.f)) * ds;
      float e1 = __expf(fminf(ct1 - cs, 0.f)) * ds;
      float v0 = (t0 >= s) ? bf2f((ushort)ra0[j]) * e0 : 0.f;
      float v1 = (t1 >= s) ? bf2f((ushort)ra1[j]) * e1 : 0.f;
      a0[j] = (short)f2bf(v0);
      a1[j] = (short)f2bf(v1);
    }
    short8 b0 = *(const short8*)(xt + (size_t)(grp*32 + l15)*8);
    short8 b1 = *(const short8*)(xt + (size_t)(grp*32 + 16 + l15)*8);
    acc[0][0] = MFMA16(a0,b0,acc[0][0]);
    acc[0][1] = MFMA16(a0,b1,acc[0][1]);
    acc[1][0] = MFMA16(a1,b0,acc[1][0]);
    acc[1][1] = MFMA16(a1,b1,acc[1][1]);
  }
  // ---- y_inter = C @ prev^T : K=n(256) ----
  f32x4 acc2[2][2] = {};
  #pragma unroll
  for (int ks = 0; ks < 8; ++ks){
    int koff = ks*32 + l4*8;
    int grp = ks*4 + l4;
    short8 a0 = *(const short8*)(bcm + (rb+t0)*512 + 256 + koff);
    short8 a1 = *(const short8*)(bcm + (rb+t1)*512 + 256 + koff);
    short8 b0 = *(const short8*)(prev + (size_t)(grp*32 + l15)*8);
    short8 b1 = *(const short8*)(prev + (size_t)(grp*32 + 16 + l15)*8);
    acc2[0][0] = MFMA16(a0,b0,acc2[0][0]);
    acc2[0][1] = MFMA16(a0,b1,acc2[0][1]);
    acc2[1][0] = MFMA16(a1,b0,acc2[1][0]);
    acc2[1][1] = MFMA16(a1,b1,acc2[1][1]);
  }
  float Dh = Dp[h];
  #pragma unroll
  for (int mt=0; mt<2; ++mt){
    int tb = wid*32 + mt*16 + l4*4;
    int tg = tb>>3, e0 = tb&7;
    #pragma unroll
    for (int nt=0; nt<2; ++nt){
      int p = nt*16 + l15;
      ushort xv[4];
      *(uint2*)xv = *(const uint2*)(xt + (size_t)(tg*32 + p)*8 + e0);
      #pragma unroll
      for (int r=0; r<4; ++r){
        int t = tb + r;
        float yv = acc[mt][nt][r] + sE[t]*acc2[mt][nt][r] + Dh*bf2f(xv[r]);
        Yb[(rb+t)*512 + h*32 + p] = f2bf(yv);
      }
    }
  }
}

// ---------------- K7: gate(silu(z)) -> RMS -> out_proj (MFMA) -------------------
__global__ __launch_bounds__(256) void k7_final(const float* __restrict__ x,
                                                char* __restrict__ wsb,
                                                float* __restrict__ out){
  int r0 = blockIdx.x*32;                  // 512 blocks
  __shared__ __align__(16) char sG[32768]; // G[32][512] bf16 rows 1024B, swizzled
  __shared__ float sScale[32];
  const ushort* Yb = (const ushort*)(wsb + OFF_Y);
  const float* M  = (const float*)(wsb + OFF_M);
  const float* Cb = (const float*)(wsb + OFF_CB_B);
  const ushort* WT = (const ushort*)(wsb + OFF_WT);
  int tid = threadIdx.x;
  int r = tid>>3, li = tid&7;
  int row = r0 + r; int b = row>>13, l = row & 8191;
  int hh, wv;
  if (l < 4096){ hh = l>>6; wv = l&63; }
  else { int l2 = l-4096; hh = 63-(l2>>6); wv = 63-(l2&63); }
  const float* xb = x + (size_t)b*12288;
  float x0 = xb[hh*64+wv], x1 = xb[4096+hh*64+wv], x2 = xb[8192+hh*64+wv];
  float sq = 0.f;
  #pragma unroll
  for (int k = 0; k < 8; ++k){
    int i0 = li*64 + k*8;
    short8 yv = *(const short8*)(Yb + (size_t)row*512 + i0);
    ushort g8[8];
    #pragma unroll
    for (int j=0;j<8;++j){
      int i = i0 + j;
      float z = Cb[i];
      z = fmaf(x0, M[i], z);
      z = fmaf(x1, M[DPROJ+i], z);
      z = fmaf(x2, M[2*DPROJ+i], z);
      float g = bf2f((ushort)yv[j]) * z * sigm(z);
      sq = fmaf(g, g, sq);
      g8[j] = f2bf(g);
    }
    *(uint4*)(sG + ((r*1024 + i0*2) ^ ((r&7)<<4))) = *(uint4*)g8;
  }
  sq += __shfl_xor(sq, 1, 64);
  sq += __shfl_xor(sq, 2, 64);
  sq += __shfl_xor(sq, 4, 64);
  if (li == 0) sScale[r] = rsqrtf(sq*(1.f/512.f) + 1e-5f);
  __syncthreads();
  int lane = tid&63, wid = tid>>6, l15 = lane&15, l4 = lane>>4;
  f32x4 acc[2][2] = {};
  #pragma unroll
  for (int ks = 0; ks < 16; ++ks){
    int kb = ks*64 + l4*16;
    int rr0 = l15, rr1 = 16+l15;
    short8 a0 = *(const short8*)(sG + ((rr0*1024 + kb) ^ ((rr0&7)<<4)));
    short8 a1 = *(const short8*)(sG + ((rr1*1024 + kb) ^ ((rr1&7)<<4)));
    int koff = ks*32 + l4*8;
    short8 b0 = *(const short8*)(WT + (size_t)(wid*32 + l15)*512 + koff);
    short8 b1 = *(const short8*)(WT + (size_t)(wid*32 + 16 + l15)*512 + koff);
    acc[0][0] = MFMA16(a0,b0,acc[0][0]);
    acc[0][1] = MFMA16(a0,b1,acc[0][1]);
    acc[1][0] = MFMA16(a1,b0,acc[1][0]);
    acc[1][1] = MFMA16(a1,b1,acc[1][1]);
  }
  #pragma unroll
  for (int mt=0; mt<2; ++mt)
  #pragma unroll
  for (int nt=0; nt<2; ++nt)
  #pragma unroll
  for (int r4=0; r4<4; ++r4){
    int rr = mt*16 + l4*4 + r4;
    int d = wid*32 + nt*16 + l15;
    out[(size_t)(r0+rr)*128 + d] = acc[mt][nt][r4] * sScale[rr];
  }
}

extern "C" void kernel_launch(void* const* d_in, const int* in_sizes, int n_in,
                              void* d_out, int out_size, void* d_ws, size_t ws_size,
                              hipStream_t stream) {
  const float* x         = (const float*)d_in[0];
  const float* fc0_w     = (const float*)d_in[1];
  const float* fc0_b     = (const float*)d_in[2];
  const float* in_proj_w = (const float*)d_in[3];
  const float* conv_w    = (const float*)d_in[4];
  const float* conv_b    = (const float*)d_in[5];
  const float* dt_bias   = (const float*)d_in[6];
  const float* A_log     = (const float*)d_in[7];
  const float* Dp        = (const float*)d_in[8];
  const float* norm_w    = (const float*)d_in[9];
  const float* out_proj_w= (const float*)d_in[10];
  char* wsb  = (char*)d_ws;
  float* out = (float*)d_out;

  k0_prep<<<dim3(7),     dim3(256), 0, stream>>>(fc0_w, fc0_b, in_proj_w, wsb);
  k0b_wt <<<dim3(128),   dim3(256), 0, stream>>>(norm_w, out_proj_w, wsb);
  k12_projconv<<<dim3(1024), dim3(256), 0, stream>>>(x, conv_w, conv_b, wsb);
  k3_cum <<<dim3(2048),  dim3(128), 0, stream>>>(x, dt_bias, A_log, wsb);
  k4a_cb <<<dim3(512),   dim3(256), 0, stream>>>(wsb);
  k4s_states<<<dim3(2048), dim3(256), 0, stream>>>(wsb);
  k5_scan<<<dim3(1024),  dim3(256), 0, stream>>>(wsb);
  k4y_out<<<dim3(2048),  dim3(256), 0, stream>>>(Dp, wsb);
  k7_final<<<dim3(512),  dim3(256), 0, stream>>>(x, wsb, out);
}